// Round 7
// baseline (328.905 us; speedup 1.0000x reference)
//
#include <hip/hip_runtime.h>
#include <hip/hip_bf16.h>

#define BB 8
#define CC 64
#define TT 128
#define PP (TT*TT)
#define C3 192

typedef __hip_bfloat16 bf16;
typedef __attribute__((ext_vector_type(8))) short short8;
typedef __attribute__((ext_vector_type(4))) float floatx4;

__device__ __forceinline__ float b2f(bf16 v){ return __bfloat162float(v); }
__device__ __forceinline__ bf16 f2b(float v){ return __float2bfloat16(v); }
__device__ __forceinline__ short8 lds8(const bf16* p){ return *(const short8*)(const void*)p; }

// ---------------------------------------------------------------------------
// k_wpk: weight prepack into MFMA A-frag lane order.
// A[m][k] frag: m = mm*16 + (lane&15), k = kk*32 + (lane>>4)*8 + j.
// wpkd = folded down-conv weights, K=256 over (s=x,hw,cw,hc)(c).
// wpkg = folded 1x1+depthwise weights: W3[oc,ic,t] = w_dw[oc,t]*w_hwc[oc,ic],
//        M=192, K=64, 9 taps. bg[cls][oc] = b_dw + b1*sum_valid(w_dw) over the
//        9 boundary classes (zero-pad applies to the conv1x1 OUTPUT == x pad).
// ---------------------------------------------------------------------------
__global__ void k_wpk(const float* __restrict__ w_down, const float* __restrict__ w_hc,
                      const float* __restrict__ w_cw,  const float* __restrict__ w_hwc,
                      const float* __restrict__ w_hw,  const float* __restrict__ w_l1,
                      const float* __restrict__ w_l2,  const float* __restrict__ w_dw,
                      const float* __restrict__ b_hwc, const float* __restrict__ b_dw,
                      bf16* __restrict__ wpkd,
                      bf16* __restrict__ wpkhw, bf16* __restrict__ wpkl1,
                      bf16* __restrict__ wpkl2, bf16* __restrict__ wpkcw,
                      bf16* __restrict__ wpkhc, bf16* __restrict__ wpkg,
                      float* __restrict__ bg){
  int i = blockIdx.x*256 + threadIdx.x;
  if (i < 147456){   // cw: t=dc*3+dw ; hc: t=dh*3+dc ; M=128,K=128
    int j = i & 7, lane = (i>>3) & 63, mm = (i>>9) & 7, kk = (i>>12) & 3, t = i >> 14;
    int m = mm*16 + (lane & 15);
    int k = kk*32 + (lane>>4)*8 + j;
    wpkcw[i] = f2b(w_cw[m*1152 + k*9 + t]);
    wpkhc[i] = f2b(w_hc[m*1152 + k*9 + t]);
  }
  if (i < 36864){    // hw/l1/l2: M=64,K=64, t=dh*3+dw
    int j = i & 7, lane = (i>>3) & 63, mm = (i>>9) & 3, kk = (i>>11) & 1, t = i >> 12;
    int oc = mm*16 + (lane & 15);
    int ic = kk*32 + (lane>>4)*8 + j;
    int s = oc*576 + ic*9 + t;
    wpkhw[i] = f2b(w_hw[s]);
    wpkl1[i] = f2b(w_l1[s]);
    wpkl2[i] = f2b(w_l2[s]);
  }
  if (i < 110592){   // g-conv folded: M=192 (mm 0..11), K=64, t=dh*3+dw
    int j = i & 7, lane = (i>>3) & 63, rest = i >> 9;
    int mm = rest % 12, tk = rest / 12;
    int oc = mm*16 + (lane & 15);
    int ic = (tk & 1)*32 + (lane>>4)*8 + j;
    int t = tk >> 1;
    wpkg[i] = f2b(w_dw[oc*9 + t] * w_hwc[oc*64 + ic]);
  }
  if (i < 1728){     // bg[cls][oc], cls = ch*3+cw, ch/cw in {0:edge-lo,1:mid,2:edge-hi}
    int cls = i / C3, oc = i % C3;
    int ch = cls / 3, cw = cls % 3;
    float S = 0.f;
    for (int dh = (ch==0?1:0); dh <= (ch==2?1:2); ++dh)
      for (int dw = (cw==0?1:0); dw <= (cw==2?1:2); ++dw)
        S += w_dw[oc*9 + dh*3 + dw];
    bg[cls*C3 + oc] = b_dw[oc] + b_hwc[oc]*S;
  }
  if (i < 16384){    // down: M=64, K=256 (kk 0..7), k = s*64+c, w = wd[s]+wd[7-s]
    int j = i & 7, lane = (i>>3) & 63, mm = (i>>9) & 3, kk = i >> 11;  // kk 0..7
    int m = mm*16 + (lane & 15);
    int k = kk*32 + (lane>>4)*8 + j;
    int s = k >> 6, c = k & 63;
    wpkd[i] = f2b(w_down[m*512 + c*8 + s] + w_down[m*512 + c*8 + 7 - s]);
  }
}

// ---------------------------------------------------------------------------
// k_pack: x(fp32 NCHW) -> xh (NHWC bf16) + xb16 (NCHW bf16), one x read.
// ---------------------------------------------------------------------------
__global__ void k_pack(const float* __restrict__ x, bf16* __restrict__ xh,
                       bf16* __restrict__ xb16){
  int h = blockIdx.x, b = blockIdx.y;
  __shared__ float xs[64][129];
  for (int idx = threadIdx.x; idx < 2048; idx += 256){
    int c = idx >> 5, w4 = (idx & 31)*4;
    float4 v = *(const float4*)(x + ((size_t)b*CC + c)*PP + h*TT + w4);
    bf16 o4[4] = { f2b(v.x), f2b(v.y), f2b(v.z), f2b(v.w) };
    *(uint2*)(xb16 + ((size_t)b*CC + c)*PP + h*TT + w4) = *(uint2*)o4;
    xs[c][w4] = v.x; xs[c][w4+1] = v.y; xs[c][w4+2] = v.z; xs[c][w4+3] = v.w;
  }
  __syncthreads();
  for (int idx = threadIdx.x; idx < 8192; idx += 256){
    int w = idx >> 6, c = idx & 63;
    xh[(((size_t)b*TT + h)*TT + w)*64 + c] = f2b(xs[c][w]);
  }
}

// xW = [b][c][w][h] bf16 (for cw conv B-operand, h contiguous).
// Reads xb16 (bit-identical to f2b(x)) -> halves read traffic vs fp32 x.
__global__ void k_xw(const bf16* __restrict__ xb16, bf16* __restrict__ xW){
  int c = blockIdx.x, b = blockIdx.y;
  __shared__ unsigned short xs2[32][140];
  const bf16* src = xb16 + ((size_t)b*CC + c)*PP;
  unsigned short* dst = (unsigned short*)(xW + ((size_t)b*CC + c)*PP);
  for (int s = 0; s < 4; ++s){
    if (s) __syncthreads();
    for (int idx = threadIdx.x; idx < 512; idx += 256){
      int hl = idx >> 4, w8 = (idx & 15)*8;
      unsigned short tmp[8];
      *(uint4*)tmp = *(const uint4*)(src + (s*32 + hl)*TT + w8);
      #pragma unroll
      for (int j = 0; j < 8; ++j) xs2[hl][w8+j] = tmp[j];
    }
    __syncthreads();
    for (int idx = threadIdx.x; idx < 4096; idx += 256){
      int w = idx >> 5, hl = idx & 31;
      dst[w*TT + s*32 + hl] = xs2[hl][w];
    }
  }
}

// ---------------------------------------------------------------------------
// k_ghwm: fused {g-conv (folded 1x1+dw, 192 oc) + hw-conv (64 oc) + HW gating}.
// Half-row tiles, wave wv owns 4 M-frags {hw[wv], g[wv](gate, reg-only),
// g[4+wv](CW), g[8+wv](HC)} x 4 N-frags; acc[4][4]=64 regs; 4 MFMA/ds_read.
// 1D grid 2*TT*NB, b = L%NB -> all blocks of batch b on one XCD.
// ---------------------------------------------------------------------------
__global__ __launch_bounds__(256)
void k_ghwm(const bf16* __restrict__ xh, const bf16* __restrict__ wpkg,
            const bf16* __restrict__ wpkhw, const float* __restrict__ bg,
            const float* __restrict__ b_hw, bf16* __restrict__ xhwh,
            bf16* __restrict__ g, int NB){
  int L = blockIdx.x;
  int b = L % NB; int r0 = L / NB;
  int h = r0 % TT; int w0b = (r0 / TT)*64;
  int tid = threadIdx.x, lane = tid & 63, wv = tid >> 6;
  int nlo = lane & 15, quad = lane >> 4;
  __shared__ bf16 xs[3][66][64];                  // 25,344 B
  for (int idx = tid; idx < 1584; idx += 256){
    int dh = idx / 528, rr = idx % 528, wi = rr >> 3, ch = rr & 7;
    int gh = h + dh - 1, gw = w0b + wi - 1;
    uint4 v = make_uint4(0,0,0,0);
    if (gh >= 0 && gh < TT && gw >= 0 && gw < TT)
      v = *(const uint4*)(xh + (((size_t)b*TT + gh)*TT + gw)*64 + ch*8);
    *(uint4*)(&xs[dh][wi][((ch ^ (wi & 7)))*8]) = v;
  }
  __syncthreads();
  floatx4 acc[4][4] = {};   // [ml: 0=hw, 1=gateHW, 2=gCW, 3=gHC][nn]
  #pragma unroll
  for (int t = 0; t < 9; ++t){
    int dh = t/3, dw = t%3;
    int swk = (nlo + dw) & 7;
    #pragma unroll
    for (int kk = 0; kk < 2; ++kk){
      int pc = ((kk*4 + quad) ^ swk)*8;
      short8 bfv[4];
      #pragma unroll
      for (int nn = 0; nn < 4; ++nn)
        bfv[nn] = lds8(&xs[dh][nn*16 + nlo + dw][pc]);
      short8 a0 = *(const short8*)(const void*)(wpkhw + (((t*2+kk)*4  + wv   )*64 + lane)*8);
      short8 a1 = *(const short8*)(const void*)(wpkg  + (((t*2+kk)*12 + wv   )*64 + lane)*8);
      short8 a2 = *(const short8*)(const void*)(wpkg  + (((t*2+kk)*12 + 4+wv )*64 + lane)*8);
      short8 a3 = *(const short8*)(const void*)(wpkg  + (((t*2+kk)*12 + 8+wv )*64 + lane)*8);
      #pragma unroll
      for (int nn = 0; nn < 4; ++nn){
        acc[0][nn] = __builtin_amdgcn_mfma_f32_16x16x32_bf16(a0, bfv[nn], acc[0][nn], 0,0,0);
        acc[1][nn] = __builtin_amdgcn_mfma_f32_16x16x32_bf16(a1, bfv[nn], acc[1][nn], 0,0,0);
        acc[2][nn] = __builtin_amdgcn_mfma_f32_16x16x32_bf16(a2, bfv[nn], acc[2][nn], 0,0,0);
        acc[3][nn] = __builtin_amdgcn_mfma_f32_16x16x32_bf16(a3, bfv[nn], acc[3][nn], 0,0,0);
      }
    }
  }
  int ch_cls3 = ((h == 0) ? 0 : (h == TT-1) ? 2 : 1)*3;
  int oc0 = wv*16 + quad*4;                       // local 0..63 within each group
  float4 bhw = *(const float4*)(b_hw + oc0);
  // --- xhwh = lrelu(hw + b_hw) * bf16(gateHW) ---
  #pragma unroll
  for (int nn = 0; nn < 4; ++nn){
    int w = w0b + nn*16 + nlo;
    int cw_cls = (w == 0) ? 0 : (w == TT-1) ? 2 : 1;
    const float* bgrow = bg + (ch_cls3 + cw_cls)*C3;
    float4 bg0 = *(const float4*)(bgrow + oc0);
    float bga[4] = { bg0.x, bg0.y, bg0.z, bg0.w };
    float bha[4] = { bhw.x, bhw.y, bhw.z, bhw.w };
    bf16 o4[4];
    #pragma unroll
    for (int r = 0; r < 4; ++r){
      float hv = acc[0][nn][r] + bha[r];
      hv = hv > 0.f ? hv : 0.1f*hv;
      float gv = b2f(f2b(acc[1][nn][r] + bga[r]));   // match old bf16 round-trip
      o4[r] = f2b(hv * gv);
    }
    *(uint2*)(xhwh + (((size_t)b*PP + h*TT + w))*64 + oc0) = *(uint2*)o4;
  }
  // --- gCW/gHC: acc -> LDS [2][64][72] -> dwordx4 NCHW stores ---
  __syncthreads();                                // all waves done with xs
  bf16* tb = &xs[0][0][0];                        // reuse: 2*64*72*2 = 18,432 B
  #pragma unroll
  for (int p = 0; p < 2; ++p){
    #pragma unroll
    for (int nn = 0; nn < 4; ++nn){
      int wl = nn*16 + nlo;
      int w = w0b + wl;
      int cw_cls = (w == 0) ? 0 : (w == TT-1) ? 2 : 1;
      float4 bgp = *(const float4*)(bg + (ch_cls3 + cw_cls)*C3 + 64 + p*64 + oc0);
      float bga[4] = { bgp.x, bgp.y, bgp.z, bgp.w };
      #pragma unroll
      for (int r = 0; r < 4; ++r)
        tb[(p*64 + oc0 + r)*72 + wl] = f2b(acc[2+p][nn][r] + bga[r]);
    }
  }
  __syncthreads();
  #pragma unroll
  for (int i = 0; i < 4; ++i){
    int idx = i*256 + tid;                        // 0..1023 = 128 rows x 8 chunks
    int row = idx >> 3, wc = (idx & 7)*8;
    uint4 v = *(const uint4*)(tb + row*72 + wc);
    *(uint4*)(g + ((size_t)b*C3 + 64 + row)*PP + h*TT + w0b + wc) = v;
  }
}

// ---------------------------------------------------------------------------
// k_c3x3m: MFMA 64->64 3x3 conv over NHWC bf16 input. Wave = ALL 4 M-frags
// (oc 0..63) x 2 N-frags (px wv*32..+32): per (t,kk) 2 ds_read feed 8 MFMA
// (was 8 ds : 8 MFMA -> LDS-read bound). acc[4][2]=32 regs.
// 1D grid TT*NB, b = L%NB (XCD locality).
// mode 1: yb NHWC = lrelu; 2: yf NCHW fp32 = lrelu+res
// ---------------------------------------------------------------------------
__global__ __launch_bounds__(256)
void k_c3x3m(const bf16* __restrict__ in, const bf16* __restrict__ wpk,
             const float* __restrict__ bias,
             const float* __restrict__ resx, bf16* __restrict__ yb,
             float* __restrict__ yf, int mode, int NB){
  int L = blockIdx.x;
  int b = L % NB, h = L / NB;
  int tid = threadIdx.x, lane = tid & 63, wv = tid >> 6;
  int nlo = lane & 15, quad = lane >> 4;
  __shared__ bf16 xs[3][130][64];
  for (int idx = tid; idx < 3120; idx += 256){
    int dh = idx / 1040, r = idx % 1040, wi = r >> 3, ch = r & 7;
    int gh = h + dh - 1, gw = wi - 1;
    uint4 v = make_uint4(0,0,0,0);
    if (gh >= 0 && gh < TT && gw >= 0 && gw < TT)
      v = *(const uint4*)(in + (((size_t)b*TT + gh)*TT + gw)*64 + ch*8);
    *(uint4*)(&xs[dh][wi][((ch ^ (wi & 7)))*8]) = v;
  }
  __syncthreads();
  floatx4 acc[4][2] = {};
  #pragma unroll
  for (int t = 0; t < 9; ++t){
    int dh = t/3, dw = t%3;
    int swk = (nlo + dw) & 7;
    #pragma unroll
    for (int kk = 0; kk < 2; ++kk){
      int pc = ((kk*4 + quad) ^ swk)*8;
      short8 bfv[2];
      #pragma unroll
      for (int nn = 0; nn < 2; ++nn)
        bfv[nn] = lds8(&xs[dh][wv*32 + nn*16 + nlo + dw][pc]);
      #pragma unroll
      for (int mm = 0; mm < 4; ++mm){
        short8 a = *(const short8*)(const void*)(wpk + (((t*2+kk)*4+mm)*64 + lane)*8);
        acc[mm][0] = __builtin_amdgcn_mfma_f32_16x16x32_bf16(a, bfv[0], acc[mm][0], 0,0,0);
        acc[mm][1] = __builtin_amdgcn_mfma_f32_16x16x32_bf16(a, bfv[1], acc[mm][1], 0,0,0);
      }
    }
  }
  #pragma unroll
  for (int mm = 0; mm < 4; ++mm){
    int oc0 = mm*16 + quad*4;
    float4 bs = *(const float4*)(bias + oc0);
    float bsa[4] = { bs.x, bs.y, bs.z, bs.w };
    #pragma unroll
    for (int nn = 0; nn < 2; ++nn){
      int w = wv*32 + nn*16 + nlo;
      int pi = h*TT + w;
      if (mode == 1){
        bf16 o4[4];
        #pragma unroll
        for (int r = 0; r < 4; ++r){
          float v = acc[mm][nn][r] + bsa[r];
          o4[r] = f2b(v > 0.f ? v : 0.1f*v);
        }
        *(uint2*)(yb + ((size_t)b*PP + pi)*64 + oc0) = *(uint2*)o4;
      } else {
        #pragma unroll
        for (int r = 0; r < 4; ++r){
          int oc = oc0 + r;
          float v = acc[mm][nn][r] + bsa[r];
          v = v > 0.f ? v : 0.1f*v;
          yf[((size_t)b*CC + oc)*PP + pi] = v + resx[((size_t)b*CC + oc)*PP + pi];
        }
      }
    }
  }
}

// ---------------------------------------------------------------------------
// k_cwm: x_cw conv via MFMA. Wave = quadrant (mg,ng): 4 ho M-frags x 2 w
// N-frags; per (tap,kk) 2 ds feed 8 MFMA (was 4 ds : 8 MFMA). acc[4][2].
// XOR-swizzled LDS. out NCHW bf16 gated. 1D grid 2*CC*NB, b = L%NB.
// ---------------------------------------------------------------------------
__global__ __launch_bounds__(256)
void k_cwm(const bf16* __restrict__ xW, const bf16* __restrict__ wpkcw,
           const float* __restrict__ bias, const bf16* __restrict__ g,
           bf16* __restrict__ xcw, int NB){
  int L = blockIdx.x;
  int b = L % NB; int r0 = L / NB;
  int c = r0 % CC; int w0b = (r0 / CC)*64;
  int tid = threadIdx.x, lane = tid & 63, wv = tid >> 6;
  int mg = wv & 1, ng = wv >> 1;
  int nlo = lane & 15, quad = lane >> 4;
  __shared__ bf16 xs[66][128];
  floatx4 acc[4][2] = {};
  for (int dc = 0; dc < 3; ++dc){
    int cc = c + dc - 1;
    if (cc < 0 || cc >= CC) continue;
    __syncthreads();
    for (int idx = tid; idx < 1056; idx += 256){
      int s = idx >> 4, ch = idx & 15;
      int gw = w0b - 1 + s;
      uint4 v = make_uint4(0,0,0,0);
      if (gw >= 0 && gw < TT)
        v = *(const uint4*)(xW + (((size_t)b*CC + cc)*TT + gw)*TT + ch*8);
      *(uint4*)(&xs[s][((ch ^ (s & 7)))*8]) = v;
    }
    __syncthreads();
    #pragma unroll
    for (int dw = 0; dw < 3; ++dw){
      int t = dc*3 + dw;
      int swk = (nlo + dw) & 7;
      #pragma unroll
      for (int kk = 0; kk < 4; ++kk){
        int pc = ((kk*4 + quad) ^ swk)*8;
        short8 bfv[2];
        #pragma unroll
        for (int nn = 0; nn < 2; ++nn)
          bfv[nn] = lds8(&xs[(ng*2+nn)*16 + nlo + dw][pc]);
        #pragma unroll
        for (int ml = 0; ml < 4; ++ml){
          short8 a = *(const short8*)(const void*)(wpkcw + (((t*4+kk)*8 + mg*4 + ml)*64 + lane)*8);
          acc[ml][0] = __builtin_amdgcn_mfma_f32_16x16x32_bf16(a, bfv[0], acc[ml][0], 0,0,0);
          acc[ml][1] = __builtin_amdgcn_mfma_f32_16x16x32_bf16(a, bfv[1], acc[ml][1], 0,0,0);
        }
      }
    }
  }
  #pragma unroll
  for (int ml = 0; ml < 4; ++ml){
    int ho0 = (mg*4 + ml)*16 + quad*4;
    float4 bs = *(const float4*)(bias + ho0);
    float bsa[4] = { bs.x, bs.y, bs.z, bs.w };
    #pragma unroll
    for (int nn = 0; nn < 2; ++nn){
      int w = w0b + (ng*2+nn)*16 + nlo;
      #pragma unroll
      for (int r = 0; r < 4; ++r){
        int ho = ho0 + r;
        float v = acc[ml][nn][r] + bsa[r];
        v = v > 0.f ? v : 0.1f*v;
        v *= b2f(g[((size_t)b*C3 + 64 + c)*PP + ho*TT + w]);
        xcw[((size_t)b*CC + c)*PP + ho*TT + w] = f2b(v);
      }
    }
  }
}

// ---------------------------------------------------------------------------
// k_hcm: x_hc conv via MFMA. Wave = quadrant (mg,ng): 4 wo M-frags x 2 c
// N-frags; per (tap,kk) 2 ds feed 8 MFMA. acc[4][2].
// XOR-swizzled LDS. out NHWC bf16 gated. 1D grid TT*NB, b = L%NB.
// ---------------------------------------------------------------------------
__global__ __launch_bounds__(256)
void k_hcm(const bf16* __restrict__ xb16, const bf16* __restrict__ wpkhc,
           const float* __restrict__ bias, const bf16* __restrict__ g,
           bf16* __restrict__ xhch, int NB){
  int L = blockIdx.x;
  int b = L % NB, h = L / NB;
  int tid = threadIdx.x, lane = tid & 63, wv = tid >> 6;
  int mg = wv & 1, ng = wv >> 1;
  int nlo = lane & 15, quad = lane >> 4;
  __shared__ bf16 xs[66][128];
  floatx4 acc[4][2] = {};
  for (int dh = 0; dh < 3; ++dh){
    int gh = h + dh - 1;
    __syncthreads();
    for (int idx = tid; idx < 1056; idx += 256){
      int s = idx >> 4, ch = idx & 15;
      int cc = s - 1;
      uint4 v = make_uint4(0,0,0,0);
      if (cc >= 0 && cc < CC && gh >= 0 && gh < TT)
        v = *(const uint4*)(xb16 + (((size_t)b*CC + cc)*TT + gh)*TT + ch*8);
      *(uint4*)(&xs[s][((ch ^ (s & 7)))*8]) = v;
    }
    __syncthreads();
    #pragma unroll
    for (int dc = 0; dc < 3; ++dc){
      int t = dh*3 + dc;
      int swk = (nlo + dc) & 7;
      #pragma unroll
      for (int kk = 0; kk < 4; ++kk){
        int pc = ((kk*4 + quad) ^ swk)*8;
        short8 bfv[2];
        #pragma unroll
        for (int nn = 0; nn < 2; ++nn)
          bfv[nn] = lds8(&xs[(ng*2+nn)*16 + nlo + dc][pc]);
        #pragma unroll
        for (int ml = 0; ml < 4; ++ml){
          short8 a = *(const short8*)(const void*)(wpkhc + (((t*4+kk)*8 + mg*4 + ml)*64 + lane)*8);
          acc[ml][0] = __builtin_amdgcn_mfma_f32_16x16x32_bf16(a, bfv[0], acc[ml][0], 0,0,0);
          acc[ml][1] = __builtin_amdgcn_mfma_f32_16x16x32_bf16(a, bfv[1], acc[ml][1], 0,0,0);
        }
      }
    }
  }
  #pragma unroll
  for (int ml = 0; ml < 4; ++ml){
    int wo0 = (mg*4 + ml)*16 + quad*4;
    float4 bs = *(const float4*)(bias + wo0);
    float bsa[4] = { bs.x, bs.y, bs.z, bs.w };
    #pragma unroll
    for (int nn = 0; nn < 2; ++nn){
      int c = (ng*2+nn)*16 + nlo;
      bf16 gg[4];
      *(uint2*)gg = *(const uint2*)(g + ((size_t)b*C3 + 128 + c)*PP + h*TT + wo0);
      #pragma unroll
      for (int r = 0; r < 4; ++r){
        float v = acc[ml][nn][r] + bsa[r];
        v = v > 0.f ? v : 0.1f*v;
        xhch[((size_t)b*PP + h*TT + wo0 + r)*64 + c] = f2b(v * b2f(gg[r]));
      }
    }
  }
}

// ---------------------------------------------------------------------------
// k_downm: folded down-conv as MFMA GEMM, K=256 over (x, x_hw, x_cw, x_hc),
// plus residual x. out NHWC bf16. grid (TT, nb), block 256.
// ---------------------------------------------------------------------------
__global__ __launch_bounds__(256)
void k_downm(const bf16* __restrict__ xh, const bf16* __restrict__ xhwh,
             const bf16* __restrict__ xcwn, const bf16* __restrict__ xhch,
             const bf16* __restrict__ wpkd, const float* __restrict__ x,
             const float* __restrict__ bias, bf16* __restrict__ outh){
  int h = blockIdx.x, b = blockIdx.y;
  int tid = threadIdx.x, lane = tid & 63, wv = tid >> 6;
  int nlo = lane & 15, quad = lane >> 4;
  int p0 = h*TT;
  __shared__ bf16 xs[128][76];
  for (int idx = tid; idx < 1024; idx += 256){
    int c = idx >> 4, w8 = (idx & 15)*8;
    bf16 tmp[8];
    *(uint4*)tmp = *(const uint4*)(xcwn + ((size_t)b*CC + c)*PP + p0 + w8);
    #pragma unroll
    for (int j = 0; j < 8; ++j) xs[w8+j][c] = tmp[j];
  }
  __syncthreads();
  int n0 = wv*32;
  floatx4 acc[4][2] = {};
  #pragma unroll
  for (int kk = 0; kk < 8; ++kk){
    int s = kk >> 1;
    int ko = (kk & 1)*32 + quad*8;
    short8 bfr[2];
    #pragma unroll
    for (int nn = 0; nn < 2; ++nn){
      int p = n0 + nn*16 + nlo;
      if (s == 2){
        bfr[nn] = lds8(&xs[p][ko]);
      } else {
        const bf16* src = (s == 0) ? xh : (s == 1) ? xhwh : xhch;
        bfr[nn] = *(const short8*)(const void*)(src + ((size_t)b*PP + p0 + p)*64 + ko);
      }
    }
    #pragma unroll
    for (int mm = 0; mm < 4; ++mm){
      short8 a = *(const short8*)(const void*)(wpkd + ((kk*4+mm)*64 + lane)*8);
      acc[mm][0] = __builtin_amdgcn_mfma_f32_16x16x32_bf16(a, bfr[0], acc[mm][0], 0,0,0);
      acc[mm][1] = __builtin_amdgcn_mfma_f32_16x16x32_bf16(a, bfr[1], acc[mm][1], 0,0,0);
    }
  }
  #pragma unroll
  for (int mm = 0; mm < 4; ++mm){
    int o0 = mm*16 + quad*4;
    float4 bs = *(const float4*)(bias + o0);
    float bsa[4] = { bs.x, bs.y, bs.z, bs.w };
    #pragma unroll
    for (int nn = 0; nn < 2; ++nn){
      int p = n0 + nn*16 + nlo;
      bf16 o4[4];
      #pragma unroll
      for (int r = 0; r < 4; ++r){
        float v = acc[mm][nn][r] + bsa[r] + x[((size_t)b*CC + o0 + r)*PP + p0 + p];
        o4[r] = f2b(v);
      }
      *(uint2*)(outh + ((size_t)b*PP + p0 + p)*64 + o0) = *(uint2*)o4;
    }
  }
}

// ---------------------------------------------------------------------------
extern "C" void kernel_launch(void* const* d_in, const int* in_sizes, int n_in,
                              void* d_out, int out_size, void* d_ws, size_t ws_size,
                              hipStream_t stream) {
  const float* x      = (const float*)d_in[0];
  const float* w_hwc  = (const float*)d_in[1];
  const float* b_hwc  = (const float*)d_in[2];
  const float* w_dw   = (const float*)d_in[3];
  const float* b_dw   = (const float*)d_in[4];
  const float* w_hw   = (const float*)d_in[5];
  const float* b_hw   = (const float*)d_in[6];
  const float* w_cw   = (const float*)d_in[7];
  const float* b_cw   = (const float*)d_in[8];
  const float* w_hc   = (const float*)d_in[9];
  const float* b_hc   = (const float*)d_in[10];
  const float* w_down = (const float*)d_in[11];
  const float* b_down = (const float*)d_in[12];
  const float* w_l1   = (const float*)d_in[13];
  const float* b_l1   = (const float*)d_in[14];
  const float* w_l2   = (const float*)d_in[15];
  const float* b_l2   = (const float*)d_in[16];
  float* out = (float*)d_out;

  char* ws = (char*)d_ws;
  // ---- meta (prepacked weights) ----
  bf16*  wpkd  = (bf16*) (ws + 0);        // 32,768 B
  float* bg    = (float*)(ws + 36864);    // 6,912
  bf16*  wpkhw = (bf16*) (ws + 65536);    // 73,728
  bf16*  wpkl1 = (bf16*) (ws + 139264);   // 73,728
  bf16*  wpkl2 = (bf16*) (ws + 212992);   // 73,728
  bf16*  wpkcw = (bf16*) (ws + 294912);   // 294,912
  bf16*  wpkhc = (bf16*) (ws + 589824);   // 294,912
  bf16*  wpkg  = (bf16*) (ws + 884736);   // 221,184 -> 1,105,920

  k_wpk<<<576, 256, 0, stream>>>(w_down, w_hc, w_cw, w_hwc, w_hw, w_l1, w_l2,
                                 w_dw, b_hwc, b_dw,
                                 wpkd, wpkhw, wpkl1, wpkl2, wpkcw, wpkhc,
                                 wpkg, bg);

  if (ws_size >= 153092096ull) {
    // ---- full-batch path (153 MB) ----
    bf16* g    = (bf16*)(ws + 2097152);     // 50,331,648 (ch 0..63 unused)
    bf16* xh   = (bf16*)(ws + 52428800);    // 16,777,216
    bf16* xW   = (bf16*)(ws + 69206016);    // 16,777,216
    bf16* xb16 = (bf16*)(ws + 85983232);    // 16,777,216
    bf16* xhwh = (bf16*)(ws + 102760448);   // 16,777,216 (NHWC)
    bf16* xcw  = (bf16*)(ws + 119537664);   // 16,777,216 (NCHW)
    bf16* xhch = (bf16*)(ws + 136314880);   // 16,777,216 (NHWC) -> 153,092,096
    bf16* outh = xW;                        // dead after k_cwm
    bf16* o1h  = xb16;                      // dead after k_hcm

    k_pack<<<dim3(TT, BB), 256, 0, stream>>>(x, xh, xb16);
    k_xw<<<dim3(CC, BB), 256, 0, stream>>>(xb16, xW);
    k_ghwm<<<2*TT*BB, 256, 0, stream>>>(xh, wpkg, wpkhw, bg, b_hw, xhwh, g, BB);
    k_cwm  <<<2*CC*BB, 256, 0, stream>>>(xW, wpkcw, b_cw, g, xcw, BB);
    k_hcm  <<<TT*BB, 256, 0, stream>>>(xb16, wpkhc, b_hc, g, xhch, BB);
    k_downm<<<dim3(TT, BB), 256, 0, stream>>>(xh, xhwh, xcw, xhch, wpkd, x, b_down, outh);
    k_c3x3m<<<TT*BB, 256, 0, stream>>>(outh, wpkl1, b_l1, nullptr, o1h, nullptr, 1, BB);
    k_c3x3m<<<TT*BB, 256, 0, stream>>>(o1h, wpkl2, b_l2, x, nullptr, out, 2, BB);
  } else {
    // ---- per-batch path (~21 MB) ----
    char* P = ws + 2097152;
    bf16* g_b    = (bf16*)(P);              //  6,291,456
    bf16* xh_b   = (bf16*)(P + 6291456);    //  2,097,152
    bf16* xW_b   = (bf16*)(P + 8388608);    //  2,097,152
    bf16* xb_b   = (bf16*)(P + 10485760);   //  2,097,152
    bf16* xhwh_b = (bf16*)(P + 12582912);   //  2,097,152
    bf16* xcw_b  = (bf16*)(P + 14680064);   //  2,097,152
    bf16* xhch_b = (bf16*)(P + 16777216);   //  2,097,152 -> 18,874,368
    bf16* outh_b = xW_b;
    bf16* o1h_b  = xb_b;
    for (int b = 0; b < BB; ++b){
      const float* xb = x + (size_t)b*CC*PP;
      float* outb = out + (size_t)b*CC*PP;
      k_pack<<<dim3(TT, 1), 256, 0, stream>>>(xb, xh_b, xb_b);
      k_xw<<<dim3(CC, 1), 256, 0, stream>>>(xb_b, xW_b);
      k_ghwm<<<2*TT, 256, 0, stream>>>(xh_b, wpkg, wpkhw, bg, b_hw, xhwh_b, g_b, 1);
      k_cwm  <<<2*CC, 256, 0, stream>>>(xW_b, wpkcw, b_cw, g_b, xcw_b, 1);
      k_hcm  <<<TT, 256, 0, stream>>>(xb_b, wpkhc, b_hc, g_b, xhch_b, 1);
      k_downm<<<dim3(TT, 1), 256, 0, stream>>>(xh_b, xhwh_b, xcw_b, xhch_b, wpkd, xb, b_down, outh_b);
      k_c3x3m<<<TT, 256, 0, stream>>>(outh_b, wpkl1, b_l1, nullptr, o1h_b, nullptr, 1, 1);
      k_c3x3m<<<TT, 256, 0, stream>>>(o1h_b, wpkl2, b_l2, xb, nullptr, outb, 2, 1);
    }
  }
}

// Round 8
// 294.472 us; speedup vs baseline: 1.1169x; 1.1169x over previous
//
#include <hip/hip_runtime.h>
#include <hip/hip_bf16.h>

#define BB 8
#define CC 64
#define TT 128
#define PP (TT*TT)
#define C3 192

typedef __hip_bfloat16 bf16;
typedef __attribute__((ext_vector_type(8))) short short8;
typedef __attribute__((ext_vector_type(4))) float floatx4;

__device__ __forceinline__ float b2f(bf16 v){ return __bfloat162float(v); }
__device__ __forceinline__ bf16 f2b(float v){ return __float2bfloat16(v); }
__device__ __forceinline__ short8 lds8(const bf16* p){ return *(const short8*)(const void*)p; }

// ---------------------------------------------------------------------------
// k_wpk: weight prepack into MFMA A-frag lane order.
// A[m][k] frag: m = mm*16 + (lane&15), k = kk*32 + (lane>>4)*8 + j.
// wpkd = folded down-conv weights, K=256 over (s=x,hw,cw,hc)(c).
// wpkg = folded 1x1+depthwise weights: W3[oc,ic,t] = w_dw[oc,t]*w_hwc[oc,ic],
//        M=192, K=64, 9 taps. bg[cls][oc] = b_dw + b1*sum_valid(w_dw) over the
//        9 boundary classes (zero-pad applies to the conv1x1 OUTPUT == x pad).
// ---------------------------------------------------------------------------
__global__ void k_wpk(const float* __restrict__ w_down, const float* __restrict__ w_hc,
                      const float* __restrict__ w_cw,  const float* __restrict__ w_hwc,
                      const float* __restrict__ w_hw,  const float* __restrict__ w_l1,
                      const float* __restrict__ w_l2,  const float* __restrict__ w_dw,
                      const float* __restrict__ b_hwc, const float* __restrict__ b_dw,
                      bf16* __restrict__ wpkd,
                      bf16* __restrict__ wpkhw, bf16* __restrict__ wpkl1,
                      bf16* __restrict__ wpkl2, bf16* __restrict__ wpkcw,
                      bf16* __restrict__ wpkhc, bf16* __restrict__ wpkg,
                      float* __restrict__ bg){
  int i = blockIdx.x*256 + threadIdx.x;
  if (i < 147456){   // cw: t=dc*3+dw ; hc: t=dh*3+dc ; M=128,K=128
    int j = i & 7, lane = (i>>3) & 63, mm = (i>>9) & 7, kk = (i>>12) & 3, t = i >> 14;
    int m = mm*16 + (lane & 15);
    int k = kk*32 + (lane>>4)*8 + j;
    wpkcw[i] = f2b(w_cw[m*1152 + k*9 + t]);
    wpkhc[i] = f2b(w_hc[m*1152 + k*9 + t]);
  }
  if (i < 36864){    // hw/l1/l2: M=64,K=64, t=dh*3+dw
    int j = i & 7, lane = (i>>3) & 63, mm = (i>>9) & 3, kk = (i>>11) & 1, t = i >> 12;
    int oc = mm*16 + (lane & 15);
    int ic = kk*32 + (lane>>4)*8 + j;
    int s = oc*576 + ic*9 + t;
    wpkhw[i] = f2b(w_hw[s]);
    wpkl1[i] = f2b(w_l1[s]);
    wpkl2[i] = f2b(w_l2[s]);
  }
  if (i < 110592){   // g-conv folded: M=192 (mm 0..11), K=64, t=dh*3+dw
    int j = i & 7, lane = (i>>3) & 63, rest = i >> 9;
    int mm = rest % 12, tk = rest / 12;
    int oc = mm*16 + (lane & 15);
    int ic = (tk & 1)*32 + (lane>>4)*8 + j;
    int t = tk >> 1;
    wpkg[i] = f2b(w_dw[oc*9 + t] * w_hwc[oc*64 + ic]);
  }
  if (i < 1728){     // bg[cls][oc], cls = ch*3+cw, ch/cw in {0:edge-lo,1:mid,2:edge-hi}
    int cls = i / C3, oc = i % C3;
    int ch = cls / 3, cw = cls % 3;
    float S = 0.f;
    for (int dh = (ch==0?1:0); dh <= (ch==2?1:2); ++dh)
      for (int dw = (cw==0?1:0); dw <= (cw==2?1:2); ++dw)
        S += w_dw[oc*9 + dh*3 + dw];
    bg[cls*C3 + oc] = b_dw[oc] + b_hwc[oc]*S;
  }
  if (i < 16384){    // down: M=64, K=256 (kk 0..7), k = s*64+c, w = wd[s]+wd[7-s]
    int j = i & 7, lane = (i>>3) & 63, mm = (i>>9) & 3, kk = i >> 11;  // kk 0..7
    int m = mm*16 + (lane & 15);
    int k = kk*32 + (lane>>4)*8 + j;
    int s = k >> 6, c = k & 63;
    wpkd[i] = f2b(w_down[m*512 + c*8 + s] + w_down[m*512 + c*8 + 7 - s]);
  }
}

// ---------------------------------------------------------------------------
// k_pack: x(fp32 NCHW) -> xh (NHWC bf16) + xb16 (NCHW bf16), one x read.
// ---------------------------------------------------------------------------
__global__ void k_pack(const float* __restrict__ x, bf16* __restrict__ xh,
                       bf16* __restrict__ xb16){
  int h = blockIdx.x, b = blockIdx.y;
  __shared__ float xs[64][129];
  for (int idx = threadIdx.x; idx < 2048; idx += 256){
    int c = idx >> 5, w4 = (idx & 31)*4;
    float4 v = *(const float4*)(x + ((size_t)b*CC + c)*PP + h*TT + w4);
    bf16 o4[4] = { f2b(v.x), f2b(v.y), f2b(v.z), f2b(v.w) };
    *(uint2*)(xb16 + ((size_t)b*CC + c)*PP + h*TT + w4) = *(uint2*)o4;
    xs[c][w4] = v.x; xs[c][w4+1] = v.y; xs[c][w4+2] = v.z; xs[c][w4+3] = v.w;
  }
  __syncthreads();
  for (int idx = threadIdx.x; idx < 8192; idx += 256){
    int w = idx >> 6, c = idx & 63;
    xh[(((size_t)b*TT + h)*TT + w)*64 + c] = f2b(xs[c][w]);
  }
}

// xW = [b][c][w][h] bf16 (for cw conv B-operand, h contiguous).
// Reads xb16 (bit-identical to f2b(x)) -> halves read traffic vs fp32 x.
__global__ void k_xw(const bf16* __restrict__ xb16, bf16* __restrict__ xW){
  int c = blockIdx.x, b = blockIdx.y;
  __shared__ unsigned short xs2[32][140];
  const bf16* src = xb16 + ((size_t)b*CC + c)*PP;
  unsigned short* dst = (unsigned short*)(xW + ((size_t)b*CC + c)*PP);
  for (int s = 0; s < 4; ++s){
    if (s) __syncthreads();
    for (int idx = threadIdx.x; idx < 512; idx += 256){
      int hl = idx >> 4, w8 = (idx & 15)*8;
      unsigned short tmp[8];
      *(uint4*)tmp = *(const uint4*)(src + (s*32 + hl)*TT + w8);
      #pragma unroll
      for (int j = 0; j < 8; ++j) xs2[hl][w8+j] = tmp[j];
    }
    __syncthreads();
    for (int idx = threadIdx.x; idx < 4096; idx += 256){
      int w = idx >> 5, hl = idx & 31;
      dst[w*TT + s*32 + hl] = xs2[hl][w];
    }
  }
}

// ---------------------------------------------------------------------------
// k_ghwm: fused {g-conv (folded 1x1+dw, 192 oc) + hw-conv (64 oc) + HW gating}.
// Half-row tiles, wave wv owns 4 M-frags {hw[wv], g[wv](gate, reg-only),
// g[4+wv](CW), g[8+wv](HC)} x 4 N-frags; acc[4][4]=64 regs; 4 MFMA/ds_read.
// 1D grid 2*TT*NB, b = L%NB -> all blocks of batch b on one XCD.
// ---------------------------------------------------------------------------
__global__ __launch_bounds__(256)
void k_ghwm(const bf16* __restrict__ xh, const bf16* __restrict__ wpkg,
            const bf16* __restrict__ wpkhw, const float* __restrict__ bg,
            const float* __restrict__ b_hw, bf16* __restrict__ xhwh,
            bf16* __restrict__ g, int NB){
  int L = blockIdx.x;
  int b = L % NB; int r0 = L / NB;
  int h = r0 % TT; int w0b = (r0 / TT)*64;
  int tid = threadIdx.x, lane = tid & 63, wv = tid >> 6;
  int nlo = lane & 15, quad = lane >> 4;
  __shared__ bf16 xs[3][66][64];                  // 25,344 B
  for (int idx = tid; idx < 1584; idx += 256){
    int dh = idx / 528, rr = idx % 528, wi = rr >> 3, ch = rr & 7;
    int gh = h + dh - 1, gw = w0b + wi - 1;
    uint4 v = make_uint4(0,0,0,0);
    if (gh >= 0 && gh < TT && gw >= 0 && gw < TT)
      v = *(const uint4*)(xh + (((size_t)b*TT + gh)*TT + gw)*64 + ch*8);
    *(uint4*)(&xs[dh][wi][((ch ^ (wi & 7)))*8]) = v;
  }
  __syncthreads();
  floatx4 acc[4][4] = {};   // [ml: 0=hw, 1=gateHW, 2=gCW, 3=gHC][nn]
  #pragma unroll
  for (int t = 0; t < 9; ++t){
    int dh = t/3, dw = t%3;
    int swk = (nlo + dw) & 7;
    #pragma unroll
    for (int kk = 0; kk < 2; ++kk){
      int pc = ((kk*4 + quad) ^ swk)*8;
      short8 bfv[4];
      #pragma unroll
      for (int nn = 0; nn < 4; ++nn)
        bfv[nn] = lds8(&xs[dh][nn*16 + nlo + dw][pc]);
      short8 a0 = *(const short8*)(const void*)(wpkhw + (((t*2+kk)*4  + wv   )*64 + lane)*8);
      short8 a1 = *(const short8*)(const void*)(wpkg  + (((t*2+kk)*12 + wv   )*64 + lane)*8);
      short8 a2 = *(const short8*)(const void*)(wpkg  + (((t*2+kk)*12 + 4+wv )*64 + lane)*8);
      short8 a3 = *(const short8*)(const void*)(wpkg  + (((t*2+kk)*12 + 8+wv )*64 + lane)*8);
      #pragma unroll
      for (int nn = 0; nn < 4; ++nn){
        acc[0][nn] = __builtin_amdgcn_mfma_f32_16x16x32_bf16(a0, bfv[nn], acc[0][nn], 0,0,0);
        acc[1][nn] = __builtin_amdgcn_mfma_f32_16x16x32_bf16(a1, bfv[nn], acc[1][nn], 0,0,0);
        acc[2][nn] = __builtin_amdgcn_mfma_f32_16x16x32_bf16(a2, bfv[nn], acc[2][nn], 0,0,0);
        acc[3][nn] = __builtin_amdgcn_mfma_f32_16x16x32_bf16(a3, bfv[nn], acc[3][nn], 0,0,0);
      }
    }
  }
  int ch_cls3 = ((h == 0) ? 0 : (h == TT-1) ? 2 : 1)*3;
  int oc0 = wv*16 + quad*4;                       // local 0..63 within each group
  float4 bhw = *(const float4*)(b_hw + oc0);
  // --- xhwh = lrelu(hw + b_hw) * bf16(gateHW) ---
  #pragma unroll
  for (int nn = 0; nn < 4; ++nn){
    int w = w0b + nn*16 + nlo;
    int cw_cls = (w == 0) ? 0 : (w == TT-1) ? 2 : 1;
    const float* bgrow = bg + (ch_cls3 + cw_cls)*C3;
    float4 bg0 = *(const float4*)(bgrow + oc0);
    float bga[4] = { bg0.x, bg0.y, bg0.z, bg0.w };
    float bha[4] = { bhw.x, bhw.y, bhw.z, bhw.w };
    bf16 o4[4];
    #pragma unroll
    for (int r = 0; r < 4; ++r){
      float hv = acc[0][nn][r] + bha[r];
      hv = hv > 0.f ? hv : 0.1f*hv;
      float gv = b2f(f2b(acc[1][nn][r] + bga[r]));   // match old bf16 round-trip
      o4[r] = f2b(hv * gv);
    }
    *(uint2*)(xhwh + (((size_t)b*PP + h*TT + w))*64 + oc0) = *(uint2*)o4;
  }
  // --- gCW/gHC: acc -> LDS [2][64][72] -> dwordx4 NCHW stores ---
  __syncthreads();                                // all waves done with xs
  bf16* tb = &xs[0][0][0];                        // reuse: 2*64*72*2 = 18,432 B
  #pragma unroll
  for (int p = 0; p < 2; ++p){
    #pragma unroll
    for (int nn = 0; nn < 4; ++nn){
      int wl = nn*16 + nlo;
      int w = w0b + wl;
      int cw_cls = (w == 0) ? 0 : (w == TT-1) ? 2 : 1;
      float4 bgp = *(const float4*)(bg + (ch_cls3 + cw_cls)*C3 + 64 + p*64 + oc0);
      float bga[4] = { bgp.x, bgp.y, bgp.z, bgp.w };
      #pragma unroll
      for (int r = 0; r < 4; ++r)
        tb[(p*64 + oc0 + r)*72 + wl] = f2b(acc[2+p][nn][r] + bga[r]);
    }
  }
  __syncthreads();
  #pragma unroll
  for (int i = 0; i < 4; ++i){
    int idx = i*256 + tid;                        // 0..1023 = 128 rows x 8 chunks
    int row = idx >> 3, wc = (idx & 7)*8;
    uint4 v = *(const uint4*)(tb + row*72 + wc);
    *(uint4*)(g + ((size_t)b*C3 + 64 + row)*PP + h*TT + w0b + wc) = v;
  }
}

// ---------------------------------------------------------------------------
// k_c3x3m: MFMA 64->64 3x3 conv over NHWC bf16 input. Wave = quadrant:
// mg=wv&1 -> 2 M-frags (oc mg*32..+32), ng=wv>>1 -> 4 N-frags (px ng*64..+64).
// Per (t,kk): 2 a-loads + 4 ds_read feed 8 MFMA (balanced: L2 36cy, LDS 32cy,
// MFMA 38cy). acc[2][4]=32 regs. 1D grid TT*NB, b = L%NB (XCD locality).
// mode 1: yb NHWC = lrelu; 2: yf NCHW fp32 = lrelu+res
// ---------------------------------------------------------------------------
__global__ __launch_bounds__(256)
void k_c3x3m(const bf16* __restrict__ in, const bf16* __restrict__ wpk,
             const float* __restrict__ bias,
             const float* __restrict__ resx, bf16* __restrict__ yb,
             float* __restrict__ yf, int mode, int NB){
  int L = blockIdx.x;
  int b = L % NB, h = L / NB;
  int tid = threadIdx.x, lane = tid & 63, wv = tid >> 6;
  int mg = wv & 1, ng = wv >> 1;
  int nlo = lane & 15, quad = lane >> 4;
  __shared__ bf16 xs[3][130][64];
  for (int idx = tid; idx < 3120; idx += 256){
    int dh = idx / 1040, r = idx % 1040, wi = r >> 3, ch = r & 7;
    int gh = h + dh - 1, gw = wi - 1;
    uint4 v = make_uint4(0,0,0,0);
    if (gh >= 0 && gh < TT && gw >= 0 && gw < TT)
      v = *(const uint4*)(in + (((size_t)b*TT + gh)*TT + gw)*64 + ch*8);
    *(uint4*)(&xs[dh][wi][((ch ^ (wi & 7)))*8]) = v;
  }
  __syncthreads();
  floatx4 acc[2][4] = {};
  #pragma unroll
  for (int t = 0; t < 9; ++t){
    int dh = t/3, dw = t%3;
    int swk = (nlo + dw) & 7;
    #pragma unroll
    for (int kk = 0; kk < 2; ++kk){
      int pc = ((kk*4 + quad) ^ swk)*8;
      short8 a0 = *(const short8*)(const void*)(wpk + (((t*2+kk)*4 + mg*2    )*64 + lane)*8);
      short8 a1 = *(const short8*)(const void*)(wpk + (((t*2+kk)*4 + mg*2 + 1)*64 + lane)*8);
      #pragma unroll
      for (int nn = 0; nn < 4; ++nn){
        short8 bfv = lds8(&xs[dh][ng*64 + nn*16 + nlo + dw][pc]);
        acc[0][nn] = __builtin_amdgcn_mfma_f32_16x16x32_bf16(a0, bfv, acc[0][nn], 0,0,0);
        acc[1][nn] = __builtin_amdgcn_mfma_f32_16x16x32_bf16(a1, bfv, acc[1][nn], 0,0,0);
      }
    }
  }
  #pragma unroll
  for (int mm = 0; mm < 2; ++mm){
    int oc0 = mg*32 + mm*16 + quad*4;
    float4 bs = *(const float4*)(bias + oc0);
    float bsa[4] = { bs.x, bs.y, bs.z, bs.w };
    #pragma unroll
    for (int nn = 0; nn < 4; ++nn){
      int w = ng*64 + nn*16 + nlo;
      int pi = h*TT + w;
      if (mode == 1){
        bf16 o4[4];
        #pragma unroll
        for (int r = 0; r < 4; ++r){
          float v = acc[mm][nn][r] + bsa[r];
          o4[r] = f2b(v > 0.f ? v : 0.1f*v);
        }
        *(uint2*)(yb + ((size_t)b*PP + pi)*64 + oc0) = *(uint2*)o4;
      } else {
        #pragma unroll
        for (int r = 0; r < 4; ++r){
          int oc = oc0 + r;
          float v = acc[mm][nn][r] + bsa[r];
          v = v > 0.f ? v : 0.1f*v;
          yf[((size_t)b*CC + oc)*PP + pi] = v + resx[((size_t)b*CC + oc)*PP + pi];
        }
      }
    }
  }
}

// ---------------------------------------------------------------------------
// k_cwm: x_cw conv via MFMA. Wave = two 16-ho M blocks, N = 64 w;
// XOR-swizzled LDS. out NCHW bf16 gated. 1D grid 2*CC*NB, b = L%NB.
// ---------------------------------------------------------------------------
__global__ __launch_bounds__(256)
void k_cwm(const bf16* __restrict__ xW, const bf16* __restrict__ wpkcw,
           const float* __restrict__ bias, const bf16* __restrict__ g,
           bf16* __restrict__ xcw, int NB){
  int L = blockIdx.x;
  int b = L % NB; int r0 = L / NB;
  int c = r0 % CC; int w0b = (r0 / CC)*64;
  int tid = threadIdx.x, lane = tid & 63, wv = tid >> 6;
  int nlo = lane & 15, quad = lane >> 4;
  __shared__ bf16 xs[66][128];
  floatx4 acc[2][4] = {};
  for (int dc = 0; dc < 3; ++dc){
    int cc = c + dc - 1;
    if (cc < 0 || cc >= CC) continue;
    __syncthreads();
    for (int idx = tid; idx < 1056; idx += 256){
      int s = idx >> 4, ch = idx & 15;
      int gw = w0b - 1 + s;
      uint4 v = make_uint4(0,0,0,0);
      if (gw >= 0 && gw < TT)
        v = *(const uint4*)(xW + (((size_t)b*CC + cc)*TT + gw)*TT + ch*8);
      *(uint4*)(&xs[s][((ch ^ (s & 7)))*8]) = v;
    }
    __syncthreads();
    #pragma unroll
    for (int dw = 0; dw < 3; ++dw){
      int t = dc*3 + dw;
      int swk = (nlo + dw) & 7;
      #pragma unroll
      for (int kk = 0; kk < 4; ++kk){
        short8 a0 = *(const short8*)(const void*)(wpkcw + (((t*4+kk)*8 + wv*2    )*64 + lane)*8);
        short8 a1 = *(const short8*)(const void*)(wpkcw + (((t*4+kk)*8 + wv*2 + 1)*64 + lane)*8);
        int pc = ((kk*4 + quad) ^ swk)*8;
        #pragma unroll
        for (int nn = 0; nn < 4; ++nn){
          short8 bf = lds8(&xs[nn*16 + nlo + dw][pc]);
          acc[0][nn] = __builtin_amdgcn_mfma_f32_16x16x32_bf16(a0, bf, acc[0][nn], 0,0,0);
          acc[1][nn] = __builtin_amdgcn_mfma_f32_16x16x32_bf16(a1, bf, acc[1][nn], 0,0,0);
        }
      }
    }
  }
  #pragma unroll
  for (int ml = 0; ml < 2; ++ml){
    int ho0 = (wv*2 + ml)*16 + quad*4;
    float4 bs = *(const float4*)(bias + ho0);
    float bsa[4] = { bs.x, bs.y, bs.z, bs.w };
    #pragma unroll
    for (int nn = 0; nn < 4; ++nn){
      int w = w0b + nn*16 + nlo;
      #pragma unroll
      for (int r = 0; r < 4; ++r){
        int ho = ho0 + r;
        float v = acc[ml][nn][r] + bsa[r];
        v = v > 0.f ? v : 0.1f*v;
        v *= b2f(g[((size_t)b*C3 + 64 + c)*PP + ho*TT + w]);
        xcw[((size_t)b*CC + c)*PP + ho*TT + w] = f2b(v);
      }
    }
  }
}

// ---------------------------------------------------------------------------
// k_hcm: x_hc conv via MFMA. Wave = two 16-wo M blocks, N = 64 c;
// XOR-swizzled LDS. out NHWC bf16 gated. 1D grid TT*NB, b = L%NB.
// ---------------------------------------------------------------------------
__global__ __launch_bounds__(256)
void k_hcm(const bf16* __restrict__ xb16, const bf16* __restrict__ wpkhc,
           const float* __restrict__ bias, const bf16* __restrict__ g,
           bf16* __restrict__ xhch, int NB){
  int L = blockIdx.x;
  int b = L % NB, h = L / NB;
  int tid = threadIdx.x, lane = tid & 63, wv = tid >> 6;
  int nlo = lane & 15, quad = lane >> 4;
  __shared__ bf16 xs[66][128];
  floatx4 acc[2][4] = {};
  for (int dh = 0; dh < 3; ++dh){
    int gh = h + dh - 1;
    __syncthreads();
    for (int idx = tid; idx < 1056; idx += 256){
      int s = idx >> 4, ch = idx & 15;
      int cc = s - 1;
      uint4 v = make_uint4(0,0,0,0);
      if (cc >= 0 && cc < CC && gh >= 0 && gh < TT)
        v = *(const uint4*)(xb16 + (((size_t)b*CC + cc)*TT + gh)*TT + ch*8);
      *(uint4*)(&xs[s][((ch ^ (s & 7)))*8]) = v;
    }
    __syncthreads();
    #pragma unroll
    for (int dc = 0; dc < 3; ++dc){
      int t = dh*3 + dc;
      int swk = (nlo + dc) & 7;
      #pragma unroll
      for (int kk = 0; kk < 4; ++kk){
        short8 a0 = *(const short8*)(const void*)(wpkhc + (((t*4+kk)*8 + wv*2    )*64 + lane)*8);
        short8 a1 = *(const short8*)(const void*)(wpkhc + (((t*4+kk)*8 + wv*2 + 1)*64 + lane)*8);
        int pc = ((kk*4 + quad) ^ swk)*8;
        #pragma unroll
        for (int nn = 0; nn < 4; ++nn){
          short8 bf = lds8(&xs[nn*16 + nlo + dc][pc]);
          acc[0][nn] = __builtin_amdgcn_mfma_f32_16x16x32_bf16(a0, bf, acc[0][nn], 0,0,0);
          acc[1][nn] = __builtin_amdgcn_mfma_f32_16x16x32_bf16(a1, bf, acc[1][nn], 0,0,0);
        }
      }
    }
  }
  #pragma unroll
  for (int ml = 0; ml < 2; ++ml){
    int wo0 = (wv*2 + ml)*16 + quad*4;
    float4 bs = *(const float4*)(bias + wo0);
    float bsa[4] = { bs.x, bs.y, bs.z, bs.w };
    #pragma unroll
    for (int nn = 0; nn < 4; ++nn){
      int c = nn*16 + nlo;
      bf16 gg[4];
      *(uint2*)gg = *(const uint2*)(g + ((size_t)b*C3 + 128 + c)*PP + h*TT + wo0);
      #pragma unroll
      for (int r = 0; r < 4; ++r){
        float v = acc[ml][nn][r] + bsa[r];
        v = v > 0.f ? v : 0.1f*v;
        xhch[((size_t)b*PP + h*TT + wo0 + r)*64 + c] = f2b(v * b2f(gg[r]));
      }
    }
  }
}

// ---------------------------------------------------------------------------
// k_downm: folded down-conv as MFMA GEMM, K=256 over (x, x_hw, x_cw, x_hc),
// plus residual x. out NHWC bf16. grid (TT, nb), block 256.
// ---------------------------------------------------------------------------
__global__ __launch_bounds__(256)
void k_downm(const bf16* __restrict__ xh, const bf16* __restrict__ xhwh,
             const bf16* __restrict__ xcwn, const bf16* __restrict__ xhch,
             const bf16* __restrict__ wpkd, const float* __restrict__ x,
             const float* __restrict__ bias, bf16* __restrict__ outh){
  int h = blockIdx.x, b = blockIdx.y;
  int tid = threadIdx.x, lane = tid & 63, wv = tid >> 6;
  int nlo = lane & 15, quad = lane >> 4;
  int p0 = h*TT;
  __shared__ bf16 xs[128][76];
  for (int idx = tid; idx < 1024; idx += 256){
    int c = idx >> 4, w8 = (idx & 15)*8;
    bf16 tmp[8];
    *(uint4*)tmp = *(const uint4*)(xcwn + ((size_t)b*CC + c)*PP + p0 + w8);
    #pragma unroll
    for (int j = 0; j < 8; ++j) xs[w8+j][c] = tmp[j];
  }
  __syncthreads();
  int n0 = wv*32;
  floatx4 acc[4][2] = {};
  #pragma unroll
  for (int kk = 0; kk < 8; ++kk){
    int s = kk >> 1;
    int ko = (kk & 1)*32 + quad*8;
    short8 bfr[2];
    #pragma unroll
    for (int nn = 0; nn < 2; ++nn){
      int p = n0 + nn*16 + nlo;
      if (s == 2){
        bfr[nn] = lds8(&xs[p][ko]);
      } else {
        const bf16* src = (s == 0) ? xh : (s == 1) ? xhwh : xhch;
        bfr[nn] = *(const short8*)(const void*)(src + ((size_t)b*PP + p0 + p)*64 + ko);
      }
    }
    #pragma unroll
    for (int mm = 0; mm < 4; ++mm){
      short8 a = *(const short8*)(const void*)(wpkd + ((kk*4+mm)*64 + lane)*8);
      acc[mm][0] = __builtin_amdgcn_mfma_f32_16x16x32_bf16(a, bfr[0], acc[mm][0], 0,0,0);
      acc[mm][1] = __builtin_amdgcn_mfma_f32_16x16x32_bf16(a, bfr[1], acc[mm][1], 0,0,0);
    }
  }
  #pragma unroll
  for (int mm = 0; mm < 4; ++mm){
    int o0 = mm*16 + quad*4;
    float4 bs = *(const float4*)(bias + o0);
    float bsa[4] = { bs.x, bs.y, bs.z, bs.w };
    #pragma unroll
    for (int nn = 0; nn < 2; ++nn){
      int p = n0 + nn*16 + nlo;
      bf16 o4[4];
      #pragma unroll
      for (int r = 0; r < 4; ++r){
        float v = acc[mm][nn][r] + bsa[r] + x[((size_t)b*CC + o0 + r)*PP + p0 + p];
        o4[r] = f2b(v);
      }
      *(uint2*)(outh + ((size_t)b*PP + p0 + p)*64 + o0) = *(uint2*)o4;
    }
  }
}

// ---------------------------------------------------------------------------
extern "C" void kernel_launch(void* const* d_in, const int* in_sizes, int n_in,
                              void* d_out, int out_size, void* d_ws, size_t ws_size,
                              hipStream_t stream) {
  const float* x      = (const float*)d_in[0];
  const float* w_hwc  = (const float*)d_in[1];
  const float* b_hwc  = (const float*)d_in[2];
  const float* w_dw   = (const float*)d_in[3];
  const float* b_dw   = (const float*)d_in[4];
  const float* w_hw   = (const float*)d_in[5];
  const float* b_hw   = (const float*)d_in[6];
  const float* w_cw   = (const float*)d_in[7];
  const float* b_cw   = (const float*)d_in[8];
  const float* w_hc   = (const float*)d_in[9];
  const float* b_hc   = (const float*)d_in[10];
  const float* w_down = (const float*)d_in[11];
  const float* b_down = (const float*)d_in[12];
  const float* w_l1   = (const float*)d_in[13];
  const float* b_l1   = (const float*)d_in[14];
  const float* w_l2   = (const float*)d_in[15];
  const float* b_l2   = (const float*)d_in[16];
  float* out = (float*)d_out;

  char* ws = (char*)d_ws;
  // ---- meta (prepacked weights) ----
  bf16*  wpkd  = (bf16*) (ws + 0);        // 32,768 B
  float* bg    = (float*)(ws + 36864);    // 6,912
  bf16*  wpkhw = (bf16*) (ws + 65536);    // 73,728
  bf16*  wpkl1 = (bf16*) (ws + 139264);   // 73,728
  bf16*  wpkl2 = (bf16*) (ws + 212992);   // 73,728
  bf16*  wpkcw = (bf16*) (ws + 294912);   // 294,912
  bf16*  wpkhc = (bf16*) (ws + 589824);   // 294,912
  bf16*  wpkg  = (bf16*) (ws + 884736);   // 221,184 -> 1,105,920

  k_wpk<<<576, 256, 0, stream>>>(w_down, w_hc, w_cw, w_hwc, w_hw, w_l1, w_l2,
                                 w_dw, b_hwc, b_dw,
                                 wpkd, wpkhw, wpkl1, wpkl2, wpkcw, wpkhc,
                                 wpkg, bg);

  if (ws_size >= 153092096ull) {
    // ---- full-batch path (153 MB) ----
    bf16* g    = (bf16*)(ws + 2097152);     // 50,331,648 (ch 0..63 unused)
    bf16* xh   = (bf16*)(ws + 52428800);    // 16,777,216
    bf16* xW   = (bf16*)(ws + 69206016);    // 16,777,216
    bf16* xb16 = (bf16*)(ws + 85983232);    // 16,777,216
    bf16* xhwh = (bf16*)(ws + 102760448);   // 16,777,216 (NHWC)
    bf16* xcw  = (bf16*)(ws + 119537664);   // 16,777,216 (NCHW)
    bf16* xhch = (bf16*)(ws + 136314880);   // 16,777,216 (NHWC) -> 153,092,096
    bf16* outh = xW;                        // dead after k_cwm
    bf16* o1h  = xb16;                      // dead after k_hcm

    k_pack<<<dim3(TT, BB), 256, 0, stream>>>(x, xh, xb16);
    k_xw<<<dim3(CC, BB), 256, 0, stream>>>(xb16, xW);
    k_ghwm<<<2*TT*BB, 256, 0, stream>>>(xh, wpkg, wpkhw, bg, b_hw, xhwh, g, BB);
    k_cwm  <<<2*CC*BB, 256, 0, stream>>>(xW, wpkcw, b_cw, g, xcw, BB);
    k_hcm  <<<TT*BB, 256, 0, stream>>>(xb16, wpkhc, b_hc, g, xhch, BB);
    k_downm<<<dim3(TT, BB), 256, 0, stream>>>(xh, xhwh, xcw, xhch, wpkd, x, b_down, outh);
    k_c3x3m<<<TT*BB, 256, 0, stream>>>(outh, wpkl1, b_l1, nullptr, o1h, nullptr, 1, BB);
    k_c3x3m<<<TT*BB, 256, 0, stream>>>(o1h, wpkl2, b_l2, x, nullptr, out, 2, BB);
  } else {
    // ---- per-batch path (~21 MB) ----
    char* P = ws + 2097152;
    bf16* g_b    = (bf16*)(P);              //  6,291,456
    bf16* xh_b   = (bf16*)(P + 6291456);    //  2,097,152
    bf16* xW_b   = (bf16*)(P + 8388608);    //  2,097,152
    bf16* xb_b   = (bf16*)(P + 10485760);   //  2,097,152
    bf16* xhwh_b = (bf16*)(P + 12582912);   //  2,097,152
    bf16* xcw_b  = (bf16*)(P + 14680064);   //  2,097,152
    bf16* xhch_b = (bf16*)(P + 16777216);   //  2,097,152 -> 18,874,368
    bf16* outh_b = xW_b;
    bf16* o1h_b  = xb_b;
    for (int b = 0; b < BB; ++b){
      const float* xb = x + (size_t)b*CC*PP;
      float* outb = out + (size_t)b*CC*PP;
      k_pack<<<dim3(TT, 1), 256, 0, stream>>>(xb, xh_b, xb_b);
      k_xw<<<dim3(CC, 1), 256, 0, stream>>>(xb_b, xW_b);
      k_ghwm<<<2*TT, 256, 0, stream>>>(xh_b, wpkg, wpkhw, bg, b_hw, xhwh_b, g_b, 1);
      k_cwm  <<<2*CC, 256, 0, stream>>>(xW_b, wpkcw, b_cw, g_b, xcw_b, 1);
      k_hcm  <<<TT, 256, 0, stream>>>(xb_b, wpkhc, b_hc, g_b, xhch_b, 1);
      k_downm<<<dim3(TT, 1), 256, 0, stream>>>(xh_b, xhwh_b, xcw_b, xhch_b, wpkd, xb, b_down, outh_b);
      k_c3x3m<<<TT, 256, 0, stream>>>(outh_b, wpkl1, b_l1, nullptr, o1h_b, nullptr, 1, 1);
      k_c3x3m<<<TT, 256, 0, stream>>>(o1h_b, wpkl2, b_l2, xb, nullptr, outb, 2, 1);
    }
  }
}

// Round 9
// 289.810 us; speedup vs baseline: 1.1349x; 1.0161x over previous
//
#include <hip/hip_runtime.h>
#include <hip/hip_bf16.h>

#define BB 8
#define CC 64
#define TT 128
#define PP (TT*TT)
#define C3 192

typedef __hip_bfloat16 bf16;
typedef __attribute__((ext_vector_type(8))) short short8;
typedef __attribute__((ext_vector_type(4))) float floatx4;

__device__ __forceinline__ float b2f(bf16 v){ return __bfloat162float(v); }
__device__ __forceinline__ bf16 f2b(float v){ return __float2bfloat16(v); }
__device__ __forceinline__ short8 lds8(const bf16* p){ return *(const short8*)(const void*)p; }

// ---------------------------------------------------------------------------
// k_wpk: weight prepack into MFMA A-frag lane order.
// A[m][k] frag: m = mm*16 + (lane&15), k = kk*32 + (lane>>4)*8 + j.
// wpkd = folded down-conv weights, K=256 over (s=x,hw,cw,hc)(c).
// wpkg = folded 1x1+depthwise weights: W3[oc,ic,t] = w_dw[oc,t]*w_hwc[oc,ic],
//        M=192, K=64, 9 taps. bg[cls][oc] = b_dw + b1*sum_valid(w_dw) over the
//        9 boundary classes (zero-pad applies to the conv1x1 OUTPUT == x pad).
// ---------------------------------------------------------------------------
__global__ void k_wpk(const float* __restrict__ w_down, const float* __restrict__ w_hc,
                      const float* __restrict__ w_cw,  const float* __restrict__ w_hwc,
                      const float* __restrict__ w_hw,  const float* __restrict__ w_l1,
                      const float* __restrict__ w_l2,  const float* __restrict__ w_dw,
                      const float* __restrict__ b_hwc, const float* __restrict__ b_dw,
                      bf16* __restrict__ wpkd,
                      bf16* __restrict__ wpkhw, bf16* __restrict__ wpkl1,
                      bf16* __restrict__ wpkl2, bf16* __restrict__ wpkcw,
                      bf16* __restrict__ wpkhc, bf16* __restrict__ wpkg,
                      float* __restrict__ bg){
  int i = blockIdx.x*256 + threadIdx.x;
  if (i < 147456){   // cw: t=dc*3+dw ; hc: t=dh*3+dc ; M=128,K=128
    int j = i & 7, lane = (i>>3) & 63, mm = (i>>9) & 7, kk = (i>>12) & 3, t = i >> 14;
    int m = mm*16 + (lane & 15);
    int k = kk*32 + (lane>>4)*8 + j;
    wpkcw[i] = f2b(w_cw[m*1152 + k*9 + t]);
    wpkhc[i] = f2b(w_hc[m*1152 + k*9 + t]);
  }
  if (i < 36864){    // hw/l1/l2: M=64,K=64, t=dh*3+dw
    int j = i & 7, lane = (i>>3) & 63, mm = (i>>9) & 3, kk = (i>>11) & 1, t = i >> 12;
    int oc = mm*16 + (lane & 15);
    int ic = kk*32 + (lane>>4)*8 + j;
    int s = oc*576 + ic*9 + t;
    wpkhw[i] = f2b(w_hw[s]);
    wpkl1[i] = f2b(w_l1[s]);
    wpkl2[i] = f2b(w_l2[s]);
  }
  if (i < 110592){   // g-conv folded: M=192 (mm 0..11), K=64, t=dh*3+dw
    int j = i & 7, lane = (i>>3) & 63, rest = i >> 9;
    int mm = rest % 12, tk = rest / 12;
    int oc = mm*16 + (lane & 15);
    int ic = (tk & 1)*32 + (lane>>4)*8 + j;
    int t = tk >> 1;
    wpkg[i] = f2b(w_dw[oc*9 + t] * w_hwc[oc*64 + ic]);
  }
  if (i < 1728){     // bg[cls][oc], cls = ch*3+cw, ch/cw in {0:edge-lo,1:mid,2:edge-hi}
    int cls = i / C3, oc = i % C3;
    int ch = cls / 3, cw = cls % 3;
    float S = 0.f;
    for (int dh = (ch==0?1:0); dh <= (ch==2?1:2); ++dh)
      for (int dw = (cw==0?1:0); dw <= (cw==2?1:2); ++dw)
        S += w_dw[oc*9 + dh*3 + dw];
    bg[cls*C3 + oc] = b_dw[oc] + b_hwc[oc]*S;
  }
  if (i < 16384){    // down: M=64, K=256 (kk 0..7), k = s*64+c, w = wd[s]+wd[7-s]
    int j = i & 7, lane = (i>>3) & 63, mm = (i>>9) & 3, kk = i >> 11;  // kk 0..7
    int m = mm*16 + (lane & 15);
    int k = kk*32 + (lane>>4)*8 + j;
    int s = k >> 6, c = k & 63;
    wpkd[i] = f2b(w_down[m*512 + c*8 + s] + w_down[m*512 + c*8 + 7 - s]);
  }
}

// ---------------------------------------------------------------------------
// k_pack: x(fp32 NCHW) -> xh (NHWC bf16) + xb16 (NCHW bf16), one x read.
// ---------------------------------------------------------------------------
__global__ void k_pack(const float* __restrict__ x, bf16* __restrict__ xh,
                       bf16* __restrict__ xb16){
  int h = blockIdx.x, b = blockIdx.y;
  __shared__ float xs[64][129];
  for (int idx = threadIdx.x; idx < 2048; idx += 256){
    int c = idx >> 5, w4 = (idx & 31)*4;
    float4 v = *(const float4*)(x + ((size_t)b*CC + c)*PP + h*TT + w4);
    bf16 o4[4] = { f2b(v.x), f2b(v.y), f2b(v.z), f2b(v.w) };
    *(uint2*)(xb16 + ((size_t)b*CC + c)*PP + h*TT + w4) = *(uint2*)o4;
    xs[c][w4] = v.x; xs[c][w4+1] = v.y; xs[c][w4+2] = v.z; xs[c][w4+3] = v.w;
  }
  __syncthreads();
  for (int idx = threadIdx.x; idx < 8192; idx += 256){
    int w = idx >> 6, c = idx & 63;
    xh[(((size_t)b*TT + h)*TT + w)*64 + c] = f2b(xs[c][w]);
  }
}

// xW = [b][c][w][h] bf16 (for cw conv B-operand, h contiguous).
// Reads xb16 (bit-identical to f2b(x)) -> halves read traffic vs fp32 x.
__global__ void k_xw(const bf16* __restrict__ xb16, bf16* __restrict__ xW){
  int c = blockIdx.x, b = blockIdx.y;
  __shared__ unsigned short xs2[32][140];
  const bf16* src = xb16 + ((size_t)b*CC + c)*PP;
  unsigned short* dst = (unsigned short*)(xW + ((size_t)b*CC + c)*PP);
  for (int s = 0; s < 4; ++s){
    if (s) __syncthreads();
    for (int idx = threadIdx.x; idx < 512; idx += 256){
      int hl = idx >> 4, w8 = (idx & 15)*8;
      unsigned short tmp[8];
      *(uint4*)tmp = *(const uint4*)(src + (s*32 + hl)*TT + w8);
      #pragma unroll
      for (int j = 0; j < 8; ++j) xs2[hl][w8+j] = tmp[j];
    }
    __syncthreads();
    for (int idx = threadIdx.x; idx < 4096; idx += 256){
      int w = idx >> 5, hl = idx & 31;
      dst[w*TT + s*32 + hl] = xs2[hl][w];
    }
  }
}

// ---------------------------------------------------------------------------
// k_ghwm: fused {g-conv (folded 1x1+dw) + hw-conv + HW gating}, M-SPLIT with
// XCD-safe decode. 1D grid 4*TT*NB: L -> b = L%NB (XCD), r = L/NB, h = r%TT,
// q = r/TT: w-half = (q&1)*64, part = q>>1. All 4 blocks of a (h,b) land on
// one XCD so the repeated halo stage is an L2 hit (R5-proven pattern).
// part 0: wave wv computes {hw[wv], g[wv](gate)} -> xhwh, no epi barriers.
// part 1: wave wv computes {g[4+wv](CW), g[8+wv](HC)} -> g via LDS transpose.
// acc[2][4]=32 regs/wave (vs 64 in merged form) -> ~5 waves/SIMD occupancy.
// Weight traffic unchanged vs merged (M-split, not N-split).
// ---------------------------------------------------------------------------
__global__ __launch_bounds__(256)
void k_ghwm(const bf16* __restrict__ xh, const bf16* __restrict__ wpkg,
            const bf16* __restrict__ wpkhw, const float* __restrict__ bg,
            const float* __restrict__ b_hw, bf16* __restrict__ xhwh,
            bf16* __restrict__ g, int NB){
  int L = blockIdx.x;
  int b = L % NB; int r0 = L / NB;
  int h = r0 % TT; int q = r0 / TT;
  int w0b = (q & 1)*64, part = q >> 1;
  int tid = threadIdx.x, lane = tid & 63, wv = tid >> 6;
  int nlo = lane & 15, quad = lane >> 4;
  __shared__ bf16 xs[3][66][64];                  // 25,344 B
  for (int idx = tid; idx < 1584; idx += 256){
    int dh = idx / 528, rr = idx % 528, wi = rr >> 3, ch = rr & 7;
    int gh = h + dh - 1, gw = w0b + wi - 1;
    uint4 v = make_uint4(0,0,0,0);
    if (gh >= 0 && gh < TT && gw >= 0 && gw < TT)
      v = *(const uint4*)(xh + (((size_t)b*TT + gh)*TT + gw)*64 + ch*8);
    *(uint4*)(&xs[dh][wi][((ch ^ (wi & 7)))*8]) = v;
  }
  __syncthreads();
  // weight streams: part 0 -> {hw[wv], g[wv]}; part 1 -> {g[4+wv], g[8+wv]}
  const bf16* pa0 = (part == 0) ? wpkhw + (size_t)wv*512
                                : wpkg  + (size_t)(4+wv)*512;
  const bf16* pa1 = (part == 0) ? wpkg + (size_t)wv*512
                                : wpkg + (size_t)(8+wv)*512;
  int sa0 = (part == 0) ? 4*512 : 12*512;
  const int sa1 = 12*512;
  floatx4 acc[2][4] = {};
  #pragma unroll
  for (int t = 0; t < 9; ++t){
    int dh = t/3, dw = t%3;
    int swk = (nlo + dw) & 7;
    #pragma unroll
    for (int kk = 0; kk < 2; ++kk){
      int t2k = t*2 + kk;
      int pc = ((kk*4 + quad) ^ swk)*8;
      short8 a0 = *(const short8*)(const void*)(pa0 + (size_t)t2k*sa0 + lane*8);
      short8 a1 = *(const short8*)(const void*)(pa1 + (size_t)t2k*sa1 + lane*8);
      #pragma unroll
      for (int nn = 0; nn < 4; ++nn){
        short8 bfv = lds8(&xs[dh][nn*16 + nlo + dw][pc]);
        acc[0][nn] = __builtin_amdgcn_mfma_f32_16x16x32_bf16(a0, bfv, acc[0][nn], 0,0,0);
        acc[1][nn] = __builtin_amdgcn_mfma_f32_16x16x32_bf16(a1, bfv, acc[1][nn], 0,0,0);
      }
    }
  }
  int ch_cls3 = ((h == 0) ? 0 : (h == TT-1) ? 2 : 1)*3;
  int oc0 = wv*16 + quad*4;                       // local 0..63 within each group
  if (part == 0){
    // --- xhwh = lrelu(hw + b_hw) * bf16(gateHW) ---
    float4 bhw = *(const float4*)(b_hw + oc0);
    float bha[4] = { bhw.x, bhw.y, bhw.z, bhw.w };
    #pragma unroll
    for (int nn = 0; nn < 4; ++nn){
      int w = w0b + nn*16 + nlo;
      int cw_cls = (w == 0) ? 0 : (w == TT-1) ? 2 : 1;
      float4 bg0 = *(const float4*)(bg + (ch_cls3 + cw_cls)*C3 + oc0);
      float bga[4] = { bg0.x, bg0.y, bg0.z, bg0.w };
      bf16 o4[4];
      #pragma unroll
      for (int r = 0; r < 4; ++r){
        float hv = acc[0][nn][r] + bha[r];
        hv = hv > 0.f ? hv : 0.1f*hv;
        float gv = b2f(f2b(acc[1][nn][r] + bga[r]));   // match old bf16 round-trip
        o4[r] = f2b(hv * gv);
      }
      *(uint2*)(xhwh + (((size_t)b*PP + h*TT + w))*64 + oc0) = *(uint2*)o4;
    }
  } else {
    // --- gCW/gHC: acc -> LDS [2][64][72] -> dwordx4 NCHW stores ---
    __syncthreads();                              // all waves done with xs
    bf16* tb = &xs[0][0][0];                      // reuse: 2*64*72*2 = 18,432 B
    #pragma unroll
    for (int p = 0; p < 2; ++p){
      #pragma unroll
      for (int nn = 0; nn < 4; ++nn){
        int wl = nn*16 + nlo;
        int w = w0b + wl;
        int cw_cls = (w == 0) ? 0 : (w == TT-1) ? 2 : 1;
        float4 bgp = *(const float4*)(bg + (ch_cls3 + cw_cls)*C3 + 64 + p*64 + oc0);
        float bga[4] = { bgp.x, bgp.y, bgp.z, bgp.w };
        #pragma unroll
        for (int r = 0; r < 4; ++r)
          tb[(p*64 + oc0 + r)*72 + wl] = f2b(acc[p][nn][r] + bga[r]);
      }
    }
    __syncthreads();
    #pragma unroll
    for (int i = 0; i < 4; ++i){
      int idx = i*256 + tid;                      // 0..1023 = 128 rows x 8 chunks
      int row = idx >> 3, wc = (idx & 7)*8;
      uint4 v = *(const uint4*)(tb + row*72 + wc);
      *(uint4*)(g + ((size_t)b*C3 + 64 + row)*PP + h*TT + w0b + wc) = v;
    }
  }
}

// ---------------------------------------------------------------------------
// k_c3x3m: MFMA 64->64 3x3 conv over NHWC bf16 input. Wave = one 16-oc M
// block, N = 128; XOR-swizzled LDS. 1D grid TT*NB, b = L%NB (XCD locality).
// (R5-proven shape: 1 A-load : 8 ds : 8 MFMA — A-loads minimized wins over
// "balanced" shapes; L2 latency hurts more than LDS throughput here.)
// mode 1: yb NHWC = lrelu; 2: yf NCHW fp32 = lrelu+res
// ---------------------------------------------------------------------------
__global__ __launch_bounds__(256)
void k_c3x3m(const bf16* __restrict__ in, const bf16* __restrict__ wpk,
             const float* __restrict__ bias,
             const float* __restrict__ resx, bf16* __restrict__ yb,
             float* __restrict__ yf, int mode, int NB){
  int L = blockIdx.x;
  int b = L % NB, h = L / NB;
  int tid = threadIdx.x, lane = tid & 63, wv = tid >> 6;
  int nlo = lane & 15, quad = lane >> 4;
  __shared__ bf16 xs[3][130][64];
  for (int idx = tid; idx < 3120; idx += 256){
    int dh = idx / 1040, r = idx % 1040, wi = r >> 3, ch = r & 7;
    int gh = h + dh - 1, gw = wi - 1;
    uint4 v = make_uint4(0,0,0,0);
    if (gh >= 0 && gh < TT && gw >= 0 && gw < TT)
      v = *(const uint4*)(in + (((size_t)b*TT + gh)*TT + gw)*64 + ch*8);
    *(uint4*)(&xs[dh][wi][((ch ^ (wi & 7)))*8]) = v;
  }
  __syncthreads();
  floatx4 acc[8] = {};
  #pragma unroll
  for (int t = 0; t < 9; ++t){
    int dh = t/3, dw = t%3;
    int swk = (nlo + dw) & 7;
    #pragma unroll
    for (int kk = 0; kk < 2; ++kk){
      short8 a = *(const short8*)(const void*)(wpk + (((t*2+kk)*4+wv)*64 + lane)*8);
      int pc = ((kk*4 + quad) ^ swk)*8;
      #pragma unroll
      for (int nn = 0; nn < 8; ++nn){
        short8 bf = lds8(&xs[dh][nn*16 + nlo + dw][pc]);
        acc[nn] = __builtin_amdgcn_mfma_f32_16x16x32_bf16(a, bf, acc[nn], 0,0,0);
      }
    }
  }
  int oc0 = wv*16 + quad*4;
  float4 bs = *(const float4*)(bias + oc0);
  float bsa[4] = { bs.x, bs.y, bs.z, bs.w };
  #pragma unroll
  for (int nn = 0; nn < 8; ++nn){
    int w = nn*16 + nlo;
    int pi = h*TT + w;
    if (mode == 1){
      bf16 o4[4];
      #pragma unroll
      for (int r = 0; r < 4; ++r){
        float v = acc[nn][r] + bsa[r];
        o4[r] = f2b(v > 0.f ? v : 0.1f*v);
      }
      *(uint2*)(yb + ((size_t)b*PP + pi)*64 + oc0) = *(uint2*)o4;
    } else {
      #pragma unroll
      for (int r = 0; r < 4; ++r){
        int oc = oc0 + r;
        float v = acc[nn][r] + bsa[r];
        v = v > 0.f ? v : 0.1f*v;
        yf[((size_t)b*CC + oc)*PP + pi] = v + resx[((size_t)b*CC + oc)*PP + pi];
      }
    }
  }
}

// ---------------------------------------------------------------------------
// k_cwm: x_cw conv via MFMA. Wave = two 16-ho M blocks, N = 64 w;
// XOR-swizzled LDS. out NCHW bf16 gated. 1D grid 2*CC*NB, b = L%NB.
// ---------------------------------------------------------------------------
__global__ __launch_bounds__(256)
void k_cwm(const bf16* __restrict__ xW, const bf16* __restrict__ wpkcw,
           const float* __restrict__ bias, const bf16* __restrict__ g,
           bf16* __restrict__ xcw, int NB){
  int L = blockIdx.x;
  int b = L % NB; int r0 = L / NB;
  int c = r0 % CC; int w0b = (r0 / CC)*64;
  int tid = threadIdx.x, lane = tid & 63, wv = tid >> 6;
  int nlo = lane & 15, quad = lane >> 4;
  __shared__ bf16 xs[66][128];
  floatx4 acc[2][4] = {};
  for (int dc = 0; dc < 3; ++dc){
    int cc = c + dc - 1;
    if (cc < 0 || cc >= CC) continue;
    __syncthreads();
    for (int idx = tid; idx < 1056; idx += 256){
      int s = idx >> 4, ch = idx & 15;
      int gw = w0b - 1 + s;
      uint4 v = make_uint4(0,0,0,0);
      if (gw >= 0 && gw < TT)
        v = *(const uint4*)(xW + (((size_t)b*CC + cc)*TT + gw)*TT + ch*8);
      *(uint4*)(&xs[s][((ch ^ (s & 7)))*8]) = v;
    }
    __syncthreads();
    #pragma unroll
    for (int dw = 0; dw < 3; ++dw){
      int t = dc*3 + dw;
      int swk = (nlo + dw) & 7;
      #pragma unroll
      for (int kk = 0; kk < 4; ++kk){
        short8 a0 = *(const short8*)(const void*)(wpkcw + (((t*4+kk)*8 + wv*2    )*64 + lane)*8);
        short8 a1 = *(const short8*)(const void*)(wpkcw + (((t*4+kk)*8 + wv*2 + 1)*64 + lane)*8);
        int pc = ((kk*4 + quad) ^ swk)*8;
        #pragma unroll
        for (int nn = 0; nn < 4; ++nn){
          short8 bf = lds8(&xs[nn*16 + nlo + dw][pc]);
          acc[0][nn] = __builtin_amdgcn_mfma_f32_16x16x32_bf16(a0, bf, acc[0][nn], 0,0,0);
          acc[1][nn] = __builtin_amdgcn_mfma_f32_16x16x32_bf16(a1, bf, acc[1][nn], 0,0,0);
        }
      }
    }
  }
  #pragma unroll
  for (int ml = 0; ml < 2; ++ml){
    int ho0 = (wv*2 + ml)*16 + quad*4;
    float4 bs = *(const float4*)(bias + ho0);
    float bsa[4] = { bs.x, bs.y, bs.z, bs.w };
    #pragma unroll
    for (int nn = 0; nn < 4; ++nn){
      int w = w0b + nn*16 + nlo;
      #pragma unroll
      for (int r = 0; r < 4; ++r){
        int ho = ho0 + r;
        float v = acc[ml][nn][r] + bsa[r];
        v = v > 0.f ? v : 0.1f*v;
        v *= b2f(g[((size_t)b*C3 + 64 + c)*PP + ho*TT + w]);
        xcw[((size_t)b*CC + c)*PP + ho*TT + w] = f2b(v);
      }
    }
  }
}

// ---------------------------------------------------------------------------
// k_hcm: x_hc conv via MFMA. Wave = two 16-wo M blocks, N = 64 c;
// XOR-swizzled LDS. out NHWC bf16 gated. 1D grid TT*NB, b = L%NB.
// ---------------------------------------------------------------------------
__global__ __launch_bounds__(256)
void k_hcm(const bf16* __restrict__ xb16, const bf16* __restrict__ wpkhc,
           const float* __restrict__ bias, const bf16* __restrict__ g,
           bf16* __restrict__ xhch, int NB){
  int L = blockIdx.x;
  int b = L % NB, h = L / NB;
  int tid = threadIdx.x, lane = tid & 63, wv = tid >> 6;
  int nlo = lane & 15, quad = lane >> 4;
  __shared__ bf16 xs[66][128];
  floatx4 acc[2][4] = {};
  for (int dh = 0; dh < 3; ++dh){
    int gh = h + dh - 1;
    __syncthreads();
    for (int idx = tid; idx < 1056; idx += 256){
      int s = idx >> 4, ch = idx & 15;
      int cc = s - 1;
      uint4 v = make_uint4(0,0,0,0);
      if (cc >= 0 && cc < CC && gh >= 0 && gh < TT)
        v = *(const uint4*)(xb16 + (((size_t)b*CC + cc)*TT + gh)*TT + ch*8);
      *(uint4*)(&xs[s][((ch ^ (s & 7)))*8]) = v;
    }
    __syncthreads();
    #pragma unroll
    for (int dc = 0; dc < 3; ++dc){
      int t = dh*3 + dc;
      int swk = (nlo + dc) & 7;
      #pragma unroll
      for (int kk = 0; kk < 4; ++kk){
        short8 a0 = *(const short8*)(const void*)(wpkhc + (((t*4+kk)*8 + wv*2    )*64 + lane)*8);
        short8 a1 = *(const short8*)(const void*)(wpkhc + (((t*4+kk)*8 + wv*2 + 1)*64 + lane)*8);
        int pc = ((kk*4 + quad) ^ swk)*8;
        #pragma unroll
        for (int nn = 0; nn < 4; ++nn){
          short8 bf = lds8(&xs[nn*16 + nlo + dc][pc]);
          acc[0][nn] = __builtin_amdgcn_mfma_f32_16x16x32_bf16(a0, bf, acc[0][nn], 0,0,0);
          acc[1][nn] = __builtin_amdgcn_mfma_f32_16x16x32_bf16(a1, bf, acc[1][nn], 0,0,0);
        }
      }
    }
  }
  #pragma unroll
  for (int ml = 0; ml < 2; ++ml){
    int wo0 = (wv*2 + ml)*16 + quad*4;
    float4 bs = *(const float4*)(bias + wo0);
    float bsa[4] = { bs.x, bs.y, bs.z, bs.w };
    #pragma unroll
    for (int nn = 0; nn < 4; ++nn){
      int c = nn*16 + nlo;
      bf16 gg[4];
      *(uint2*)gg = *(const uint2*)(g + ((size_t)b*C3 + 128 + c)*PP + h*TT + wo0);
      #pragma unroll
      for (int r = 0; r < 4; ++r){
        float v = acc[ml][nn][r] + bsa[r];
        v = v > 0.f ? v : 0.1f*v;
        xhch[((size_t)b*PP + h*TT + wo0 + r)*64 + c] = f2b(v * b2f(gg[r]));
      }
    }
  }
}

// ---------------------------------------------------------------------------
// k_downm: folded down-conv as MFMA GEMM, K=256 over (x, x_hw, x_cw, x_hc),
// plus residual x. out NHWC bf16. grid (TT, nb), block 256.
// ---------------------------------------------------------------------------
__global__ __launch_bounds__(256)
void k_downm(const bf16* __restrict__ xh, const bf16* __restrict__ xhwh,
             const bf16* __restrict__ xcwn, const bf16* __restrict__ xhch,
             const bf16* __restrict__ wpkd, const float* __restrict__ x,
             const float* __restrict__ bias, bf16* __restrict__ outh){
  int h = blockIdx.x, b = blockIdx.y;
  int tid = threadIdx.x, lane = tid & 63, wv = tid >> 6;
  int nlo = lane & 15, quad = lane >> 4;
  int p0 = h*TT;
  __shared__ bf16 xs[128][76];
  for (int idx = tid; idx < 1024; idx += 256){
    int c = idx >> 4, w8 = (idx & 15)*8;
    bf16 tmp[8];
    *(uint4*)tmp = *(const uint4*)(xcwn + ((size_t)b*CC + c)*PP + p0 + w8);
    #pragma unroll
    for (int j = 0; j < 8; ++j) xs[w8+j][c] = tmp[j];
  }
  __syncthreads();
  int n0 = wv*32;
  floatx4 acc[4][2] = {};
  #pragma unroll
  for (int kk = 0; kk < 8; ++kk){
    int s = kk >> 1;
    int ko = (kk & 1)*32 + quad*8;
    short8 bfr[2];
    #pragma unroll
    for (int nn = 0; nn < 2; ++nn){
      int p = n0 + nn*16 + nlo;
      if (s == 2){
        bfr[nn] = lds8(&xs[p][ko]);
      } else {
        const bf16* src = (s == 0) ? xh : (s == 1) ? xhwh : xhch;
        bfr[nn] = *(const short8*)(const void*)(src + ((size_t)b*PP + p0 + p)*64 + ko);
      }
    }
    #pragma unroll
    for (int mm = 0; mm < 4; ++mm){
      short8 a = *(const short8*)(const void*)(wpkd + ((kk*4+mm)*64 + lane)*8);
      acc[mm][0] = __builtin_amdgcn_mfma_f32_16x16x32_bf16(a, bfr[0], acc[mm][0], 0,0,0);
      acc[mm][1] = __builtin_amdgcn_mfma_f32_16x16x32_bf16(a, bfr[1], acc[mm][1], 0,0,0);
    }
  }
  #pragma unroll
  for (int mm = 0; mm < 4; ++mm){
    int o0 = mm*16 + quad*4;
    float4 bs = *(const float4*)(bias + o0);
    float bsa[4] = { bs.x, bs.y, bs.z, bs.w };
    #pragma unroll
    for (int nn = 0; nn < 2; ++nn){
      int p = n0 + nn*16 + nlo;
      bf16 o4[4];
      #pragma unroll
      for (int r = 0; r < 4; ++r){
        float v = acc[mm][nn][r] + bsa[r] + x[((size_t)b*CC + o0 + r)*PP + p0 + p];
        o4[r] = f2b(v);
      }
      *(uint2*)(outh + ((size_t)b*PP + p0 + p)*64 + o0) = *(uint2*)o4;
    }
  }
}

// ---------------------------------------------------------------------------
extern "C" void kernel_launch(void* const* d_in, const int* in_sizes, int n_in,
                              void* d_out, int out_size, void* d_ws, size_t ws_size,
                              hipStream_t stream) {
  const float* x      = (const float*)d_in[0];
  const float* w_hwc  = (const float*)d_in[1];
  const float* b_hwc  = (const float*)d_in[2];
  const float* w_dw   = (const float*)d_in[3];
  const float* b_dw   = (const float*)d_in[4];
  const float* w_hw   = (const float*)d_in[5];
  const float* b_hw   = (const float*)d_in[6];
  const float* w_cw   = (const float*)d_in[7];
  const float* b_cw   = (const float*)d_in[8];
  const float* w_hc   = (const float*)d_in[9];
  const float* b_hc   = (const float*)d_in[10];
  const float* w_down = (const float*)d_in[11];
  const float* b_down = (const float*)d_in[12];
  const float* w_l1   = (const float*)d_in[13];
  const float* b_l1   = (const float*)d_in[14];
  const float* w_l2   = (const float*)d_in[15];
  const float* b_l2   = (const float*)d_in[16];
  float* out = (float*)d_out;

  char* ws = (char*)d_ws;
  // ---- meta (prepacked weights) ----
  bf16*  wpkd  = (bf16*) (ws + 0);        // 32,768 B
  float* bg    = (float*)(ws + 36864);    // 6,912
  bf16*  wpkhw = (bf16*) (ws + 65536);    // 73,728
  bf16*  wpkl1 = (bf16*) (ws + 139264);   // 73,728
  bf16*  wpkl2 = (bf16*) (ws + 212992);   // 73,728
  bf16*  wpkcw = (bf16*) (ws + 294912);   // 294,912
  bf16*  wpkhc = (bf16*) (ws + 589824);   // 294,912
  bf16*  wpkg  = (bf16*) (ws + 884736);   // 221,184 -> 1,105,920

  k_wpk<<<576, 256, 0, stream>>>(w_down, w_hc, w_cw, w_hwc, w_hw, w_l1, w_l2,
                                 w_dw, b_hwc, b_dw,
                                 wpkd, wpkhw, wpkl1, wpkl2, wpkcw, wpkhc,
                                 wpkg, bg);

  if (ws_size >= 153092096ull) {
    // ---- full-batch path (153 MB) ----
    bf16* g    = (bf16*)(ws + 2097152);     // 50,331,648 (ch 0..63 unused)
    bf16* xh   = (bf16*)(ws + 52428800);    // 16,777,216
    bf16* xW   = (bf16*)(ws + 69206016);    // 16,777,216
    bf16* xb16 = (bf16*)(ws + 85983232);    // 16,777,216
    bf16* xhwh = (bf16*)(ws + 102760448);   // 16,777,216 (NHWC)
    bf16* xcw  = (bf16*)(ws + 119537664);   // 16,777,216 (NCHW)
    bf16* xhch = (bf16*)(ws + 136314880);   // 16,777,216 (NHWC) -> 153,092,096
    bf16* outh = xW;                        // dead after k_cwm
    bf16* o1h  = xb16;                      // dead after k_hcm

    k_pack<<<dim3(TT, BB), 256, 0, stream>>>(x, xh, xb16);
    k_xw<<<dim3(CC, BB), 256, 0, stream>>>(xb16, xW);
    k_ghwm<<<4*TT*BB, 256, 0, stream>>>(xh, wpkg, wpkhw, bg, b_hw, xhwh, g, BB);
    k_cwm  <<<2*CC*BB, 256, 0, stream>>>(xW, wpkcw, b_cw, g, xcw, BB);
    k_hcm  <<<TT*BB, 256, 0, stream>>>(xb16, wpkhc, b_hc, g, xhch, BB);
    k_downm<<<dim3(TT, BB), 256, 0, stream>>>(xh, xhwh, xcw, xhch, wpkd, x, b_down, outh);
    k_c3x3m<<<TT*BB, 256, 0, stream>>>(outh, wpkl1, b_l1, nullptr, o1h, nullptr, 1, BB);
    k_c3x3m<<<TT*BB, 256, 0, stream>>>(o1h, wpkl2, b_l2, x, nullptr, out, 2, BB);
  } else {
    // ---- per-batch path (~21 MB) ----
    char* P = ws + 2097152;
    bf16* g_b    = (bf16*)(P);              //  6,291,456
    bf16* xh_b   = (bf16*)(P + 6291456);    //  2,097,152
    bf16* xW_b   = (bf16*)(P + 8388608);    //  2,097,152
    bf16* xb_b   = (bf16*)(P + 10485760);   //  2,097,152
    bf16* xhwh_b = (bf16*)(P + 12582912);   //  2,097,152
    bf16* xcw_b  = (bf16*)(P + 14680064);   //  2,097,152
    bf16* xhch_b = (bf16*)(P + 16777216);   //  2,097,152 -> 18,874,368
    bf16* outh_b = xW_b;
    bf16* o1h_b  = xb_b;
    for (int b = 0; b < BB; ++b){
      const float* xb = x + (size_t)b*CC*PP;
      float* outb = out + (size_t)b*CC*PP;
      k_pack<<<dim3(TT, 1), 256, 0, stream>>>(xb, xh_b, xb_b);
      k_xw<<<dim3(CC, 1), 256, 0, stream>>>(xb_b, xW_b);
      k_ghwm<<<4*TT, 256, 0, stream>>>(xh_b, wpkg, wpkhw, bg, b_hw, xhwh_b, g_b, 1);
      k_cwm  <<<2*CC, 256, 0, stream>>>(xW_b, wpkcw, b_cw, g_b, xcw_b, 1);
      k_hcm  <<<TT, 256, 0, stream>>>(xb_b, wpkhc, b_hc, g_b, xhch_b, 1);
      k_downm<<<dim3(TT, 1), 256, 0, stream>>>(xh_b, xhwh_b, xcw_b, xhch_b, wpkd, xb, b_down, outh_b);
      k_c3x3m<<<TT, 256, 0, stream>>>(outh_b, wpkl1, b_l1, nullptr, o1h_b, nullptr, 1, 1);
      k_c3x3m<<<TT, 256, 0, stream>>>(o1h_b, wpkl2, b_l2, xb, nullptr, outb, 2, 1);
    }
  }
}

// Round 10
// 285.803 us; speedup vs baseline: 1.1508x; 1.0140x over previous
//
#include <hip/hip_runtime.h>
#include <hip/hip_bf16.h>

#define BB 8
#define CC 64
#define TT 128
#define PP (TT*TT)
#define C3 192

typedef __hip_bfloat16 bf16;
typedef __attribute__((ext_vector_type(8))) short short8;
typedef __attribute__((ext_vector_type(4))) float floatx4;

__device__ __forceinline__ float b2f(bf16 v){ return __bfloat162float(v); }
__device__ __forceinline__ bf16 f2b(float v){ return __float2bfloat16(v); }
__device__ __forceinline__ short8 lds8(const bf16* p){ return *(const short8*)(const void*)p; }

// ---------------------------------------------------------------------------
// k_wpk: weight prepack into MFMA A-frag lane order.
// A[m][k] frag: m = mm*16 + (lane&15), k = kk*32 + (lane>>4)*8 + j.
// wpkd = folded down-conv weights, K=256 over (s=x,hw,cw,hc)(c).
// wpkg/wpkgm = folded 1x1+dw weights: W3[oc,ic,t] = w_dw[oc,t]*w_hwc[oc,ic].
// wpkgm = ghwm stream-major layout [wv][t2k][s][lane][8]: per (t,kk) a wave's
//         4 A-frags are 4 consecutive KB -> one base + imm offsets (VALU cut).
// bg[cls][oc] = b_dw + b1*sum_valid(w_dw) over 9 boundary classes.
// ---------------------------------------------------------------------------
__global__ void k_wpk(const float* __restrict__ w_down, const float* __restrict__ w_hc,
                      const float* __restrict__ w_cw,  const float* __restrict__ w_hwc,
                      const float* __restrict__ w_hw,  const float* __restrict__ w_l1,
                      const float* __restrict__ w_l2,  const float* __restrict__ w_dw,
                      const float* __restrict__ b_hwc, const float* __restrict__ b_dw,
                      bf16* __restrict__ wpkd,
                      bf16* __restrict__ wpkhw, bf16* __restrict__ wpkl1,
                      bf16* __restrict__ wpkl2, bf16* __restrict__ wpkcw,
                      bf16* __restrict__ wpkhc, bf16* __restrict__ wpkgm,
                      float* __restrict__ bg){
  int i = blockIdx.x*256 + threadIdx.x;
  if (i < 147456){   // cw: t=dc*3+dw ; hc: t=dh*3+dc ; M=128,K=128
    int j = i & 7, lane = (i>>3) & 63, mm = (i>>9) & 7, kk = (i>>12) & 3, t = i >> 14;
    int m = mm*16 + (lane & 15);
    int k = kk*32 + (lane>>4)*8 + j;
    wpkcw[i] = f2b(w_cw[m*1152 + k*9 + t]);
    wpkhc[i] = f2b(w_hc[m*1152 + k*9 + t]);
  }
  if (i < 147456){   // ghwm stream-major: i = ((wv*18+t2k)*4+s)*512 + lane*8 + j
    int j = i & 7, lane = (i>>3) & 63, s = (i>>9) & 3;
    int rest = i >> 11;
    int t2k = rest % 18, wv = rest / 18;
    int t = t2k >> 1, kk = t2k & 1;
    int lm = lane & 15;
    int ic = kk*32 + (lane>>4)*8 + j;
    float val;
    if (s == 0){
      val = w_hw[(wv*16 + lm)*576 + ic*9 + t];
    } else {
      int grp = (s == 1) ? wv : (s == 2) ? 4 + wv : 8 + wv;
      int oc = grp*16 + lm;
      val = w_dw[oc*9 + t] * w_hwc[oc*64 + ic];
    }
    wpkgm[i] = f2b(val);
  }
  if (i < 36864){    // hw/l1/l2: M=64,K=64, t=dh*3+dw
    int j = i & 7, lane = (i>>3) & 63, mm = (i>>9) & 3, kk = (i>>11) & 1, t = i >> 12;
    int oc = mm*16 + (lane & 15);
    int ic = kk*32 + (lane>>4)*8 + j;
    int s = oc*576 + ic*9 + t;
    wpkhw[i] = f2b(w_hw[s]);
    wpkl1[i] = f2b(w_l1[s]);
    wpkl2[i] = f2b(w_l2[s]);
  }
  if (i < 1728){     // bg[cls][oc], cls = ch*3+cw, ch/cw in {0:edge-lo,1:mid,2:edge-hi}
    int cls = i / C3, oc = i % C3;
    int ch = cls / 3, cw = cls % 3;
    float S = 0.f;
    for (int dh = (ch==0?1:0); dh <= (ch==2?1:2); ++dh)
      for (int dw = (cw==0?1:0); dw <= (cw==2?1:2); ++dw)
        S += w_dw[oc*9 + dh*3 + dw];
    bg[cls*C3 + oc] = b_dw[oc] + b_hwc[oc]*S;
  }
  if (i < 16384){    // down: M=64, K=256 (kk 0..7), k = s*64+c, w = wd[s]+wd[7-s]
    int j = i & 7, lane = (i>>3) & 63, mm = (i>>9) & 3, kk = i >> 11;  // kk 0..7
    int m = mm*16 + (lane & 15);
    int k = kk*32 + (lane>>4)*8 + j;
    int s = k >> 6, c = k & 63;
    wpkd[i] = f2b(w_down[m*512 + c*8 + s] + w_down[m*512 + c*8 + 7 - s]);
  }
}

// ---------------------------------------------------------------------------
// k_pack: x(fp32 NCHW) -> xh (NHWC bf16) + xb16 (NCHW bf16), one x read.
// ---------------------------------------------------------------------------
__global__ void k_pack(const float* __restrict__ x, bf16* __restrict__ xh,
                       bf16* __restrict__ xb16){
  int h = blockIdx.x, b = blockIdx.y;
  __shared__ float xs[64][129];
  for (int idx = threadIdx.x; idx < 2048; idx += 256){
    int c = idx >> 5, w4 = (idx & 31)*4;
    float4 v = *(const float4*)(x + ((size_t)b*CC + c)*PP + h*TT + w4);
    bf16 o4[4] = { f2b(v.x), f2b(v.y), f2b(v.z), f2b(v.w) };
    *(uint2*)(xb16 + ((size_t)b*CC + c)*PP + h*TT + w4) = *(uint2*)o4;
    xs[c][w4] = v.x; xs[c][w4+1] = v.y; xs[c][w4+2] = v.z; xs[c][w4+3] = v.w;
  }
  __syncthreads();
  for (int idx = threadIdx.x; idx < 8192; idx += 256){
    int w = idx >> 6, c = idx & 63;
    xh[(((size_t)b*TT + h)*TT + w)*64 + c] = f2b(xs[c][w]);
  }
}

// xW = [b][c][w][h] bf16 (for cw conv B-operand, h contiguous).
// Reads xb16 (bit-identical to f2b(x)) -> halves read traffic vs fp32 x.
__global__ void k_xw(const bf16* __restrict__ xb16, bf16* __restrict__ xW){
  int c = blockIdx.x, b = blockIdx.y;
  __shared__ unsigned short xs2[32][140];
  const bf16* src = xb16 + ((size_t)b*CC + c)*PP;
  unsigned short* dst = (unsigned short*)(xW + ((size_t)b*CC + c)*PP);
  for (int s = 0; s < 4; ++s){
    if (s) __syncthreads();
    for (int idx = threadIdx.x; idx < 512; idx += 256){
      int hl = idx >> 4, w8 = (idx & 15)*8;
      unsigned short tmp[8];
      *(uint4*)tmp = *(const uint4*)(src + (s*32 + hl)*TT + w8);
      #pragma unroll
      for (int j = 0; j < 8; ++j) xs2[hl][w8+j] = tmp[j];
    }
    __syncthreads();
    for (int idx = threadIdx.x; idx < 4096; idx += 256){
      int w = idx >> 5, hl = idx & 31;
      dst[w*TT + s*32 + hl] = xs2[hl][w];
    }
  }
}

// ---------------------------------------------------------------------------
// k_ghwm: fused {g-conv (folded 1x1+dw, 192 oc) + hw-conv (64 oc) + HW gating}.
// R5-proven merged form: half-row tiles, wave wv owns 4 M-frags {hw[wv],
// g[wv](gate, reg-only), g[4+wv](CW), g[8+wv](HC)} x 4 N-frags; acc[4][4].
// Weights via stream-major wpkgm: per (t,kk) one base + imm offsets 0/1/2/3KB.
// 1D grid 2*TT*NB, b = L%NB -> all blocks of batch b on one XCD.
// ---------------------------------------------------------------------------
__global__ __launch_bounds__(256)
void k_ghwm(const bf16* __restrict__ xh, const bf16* __restrict__ wpkgm,
            const float* __restrict__ bg,
            const float* __restrict__ b_hw, bf16* __restrict__ xhwh,
            bf16* __restrict__ g, int NB){
  int L = blockIdx.x;
  int b = L % NB; int r0 = L / NB;
  int h = r0 % TT; int w0b = (r0 / TT)*64;
  int tid = threadIdx.x, lane = tid & 63, wv = tid >> 6;
  int nlo = lane & 15, quad = lane >> 4;
  __shared__ bf16 xs[3][66][64];                  // 25,344 B
  for (int idx = tid; idx < 1584; idx += 256){
    int dh = idx / 528, rr = idx % 528, wi = rr >> 3, ch = rr & 7;
    int gh = h + dh - 1, gw = w0b + wi - 1;
    uint4 v = make_uint4(0,0,0,0);
    if (gh >= 0 && gh < TT && gw >= 0 && gw < TT)
      v = *(const uint4*)(xh + (((size_t)b*TT + gh)*TT + gw)*64 + ch*8);
    *(uint4*)(&xs[dh][wi][((ch ^ (wi & 7)))*8]) = v;
  }
  __syncthreads();
  const bf16* pa = wpkgm + (size_t)wv*36864 + lane*8;   // [wv][t2k][s][lane][8]
  floatx4 acc[4][4] = {};   // [ml: 0=hw, 1=gateHW, 2=gCW, 3=gHC][nn]
  #pragma unroll
  for (int t = 0; t < 9; ++t){
    int dh = t/3, dw = t%3;
    int swk = (nlo + dw) & 7;
    #pragma unroll
    for (int kk = 0; kk < 2; ++kk){
      int pc = ((kk*4 + quad) ^ swk)*8;
      short8 bfv[4];
      #pragma unroll
      for (int nn = 0; nn < 4; ++nn)
        bfv[nn] = lds8(&xs[dh][nn*16 + nlo + dw][pc]);
      const bf16* base = pa + (t*2 + kk)*2048;
      short8 a0 = *(const short8*)(const void*)(base);
      short8 a1 = *(const short8*)(const void*)(base + 512);
      short8 a2 = *(const short8*)(const void*)(base + 1024);
      short8 a3 = *(const short8*)(const void*)(base + 1536);
      #pragma unroll
      for (int nn = 0; nn < 4; ++nn){
        acc[0][nn] = __builtin_amdgcn_mfma_f32_16x16x32_bf16(a0, bfv[nn], acc[0][nn], 0,0,0);
        acc[1][nn] = __builtin_amdgcn_mfma_f32_16x16x32_bf16(a1, bfv[nn], acc[1][nn], 0,0,0);
        acc[2][nn] = __builtin_amdgcn_mfma_f32_16x16x32_bf16(a2, bfv[nn], acc[2][nn], 0,0,0);
        acc[3][nn] = __builtin_amdgcn_mfma_f32_16x16x32_bf16(a3, bfv[nn], acc[3][nn], 0,0,0);
      }
    }
  }
  int ch_cls3 = ((h == 0) ? 0 : (h == TT-1) ? 2 : 1)*3;
  int oc0 = wv*16 + quad*4;                       // local 0..63 within each group
  float4 bhw = *(const float4*)(b_hw + oc0);
  // --- xhwh = lrelu(hw + b_hw) * bf16(gateHW) ---
  #pragma unroll
  for (int nn = 0; nn < 4; ++nn){
    int w = w0b + nn*16 + nlo;
    int cw_cls = (w == 0) ? 0 : (w == TT-1) ? 2 : 1;
    const float* bgrow = bg + (ch_cls3 + cw_cls)*C3;
    float4 bg0 = *(const float4*)(bgrow + oc0);
    float bga[4] = { bg0.x, bg0.y, bg0.z, bg0.w };
    float bha[4] = { bhw.x, bhw.y, bhw.z, bhw.w };
    bf16 o4[4];
    #pragma unroll
    for (int r = 0; r < 4; ++r){
      float hv = acc[0][nn][r] + bha[r];
      hv = hv > 0.f ? hv : 0.1f*hv;
      float gv = b2f(f2b(acc[1][nn][r] + bga[r]));   // match old bf16 round-trip
      o4[r] = f2b(hv * gv);
    }
    *(uint2*)(xhwh + (((size_t)b*PP + h*TT + w))*64 + oc0) = *(uint2*)o4;
  }
  // --- gCW/gHC: acc -> LDS [2][64][72] -> dwordx4 NCHW stores ---
  __syncthreads();                                // all waves done with xs
  bf16* tb = &xs[0][0][0];                        // reuse: 2*64*72*2 = 18,432 B
  #pragma unroll
  for (int p = 0; p < 2; ++p){
    #pragma unroll
    for (int nn = 0; nn < 4; ++nn){
      int wl = nn*16 + nlo;
      int w = w0b + wl;
      int cw_cls = (w == 0) ? 0 : (w == TT-1) ? 2 : 1;
      float4 bgp = *(const float4*)(bg + (ch_cls3 + cw_cls)*C3 + 64 + p*64 + oc0);
      float bga[4] = { bgp.x, bgp.y, bgp.z, bgp.w };
      #pragma unroll
      for (int r = 0; r < 4; ++r)
        tb[(p*64 + oc0 + r)*72 + wl] = f2b(acc[2+p][nn][r] + bga[r]);
    }
  }
  __syncthreads();
  #pragma unroll
  for (int i = 0; i < 4; ++i){
    int idx = i*256 + tid;                        // 0..1023 = 128 rows x 8 chunks
    int row = idx >> 3, wc = (idx & 7)*8;
    uint4 v = *(const uint4*)(tb + row*72 + wc);
    *(uint4*)(g + ((size_t)b*C3 + 64 + row)*PP + h*TT + w0b + wc) = v;
  }
}

// ---------------------------------------------------------------------------
// k_c3x3m: MFMA 64->64 3x3 conv over NHWC bf16 input. Wave = one 16-oc M
// block, N = 128; XOR-swizzled LDS. 1D grid TT*NB, b = L%NB (XCD locality).
// (R5-proven shape: A-loads minimized; L2 latency hurts more than LDS BW.)
// mode 1: yb NHWC = lrelu; 2: yf NCHW fp32 = lrelu+res
// ---------------------------------------------------------------------------
__global__ __launch_bounds__(256)
void k_c3x3m(const bf16* __restrict__ in, const bf16* __restrict__ wpk,
             const float* __restrict__ bias,
             const float* __restrict__ resx, bf16* __restrict__ yb,
             float* __restrict__ yf, int mode, int NB){
  int L = blockIdx.x;
  int b = L % NB, h = L / NB;
  int tid = threadIdx.x, lane = tid & 63, wv = tid >> 6;
  int nlo = lane & 15, quad = lane >> 4;
  __shared__ bf16 xs[3][130][64];
  for (int idx = tid; idx < 3120; idx += 256){
    int dh = idx / 1040, r = idx % 1040, wi = r >> 3, ch = r & 7;
    int gh = h + dh - 1, gw = wi - 1;
    uint4 v = make_uint4(0,0,0,0);
    if (gh >= 0 && gh < TT && gw >= 0 && gw < TT)
      v = *(const uint4*)(in + (((size_t)b*TT + gh)*TT + gw)*64 + ch*8);
    *(uint4*)(&xs[dh][wi][((ch ^ (wi & 7)))*8]) = v;
  }
  __syncthreads();
  floatx4 acc[8] = {};
  #pragma unroll
  for (int t = 0; t < 9; ++t){
    int dh = t/3, dw = t%3;
    int swk = (nlo + dw) & 7;
    #pragma unroll
    for (int kk = 0; kk < 2; ++kk){
      short8 a = *(const short8*)(const void*)(wpk + (((t*2+kk)*4+wv)*64 + lane)*8);
      int pc = ((kk*4 + quad) ^ swk)*8;
      #pragma unroll
      for (int nn = 0; nn < 8; ++nn){
        short8 bf = lds8(&xs[dh][nn*16 + nlo + dw][pc]);
        acc[nn] = __builtin_amdgcn_mfma_f32_16x16x32_bf16(a, bf, acc[nn], 0,0,0);
      }
    }
  }
  int oc0 = wv*16 + quad*4;
  float4 bs = *(const float4*)(bias + oc0);
  float bsa[4] = { bs.x, bs.y, bs.z, bs.w };
  #pragma unroll
  for (int nn = 0; nn < 8; ++nn){
    int w = nn*16 + nlo;
    int pi = h*TT + w;
    if (mode == 1){
      bf16 o4[4];
      #pragma unroll
      for (int r = 0; r < 4; ++r){
        float v = acc[nn][r] + bsa[r];
        o4[r] = f2b(v > 0.f ? v : 0.1f*v);
      }
      *(uint2*)(yb + ((size_t)b*PP + pi)*64 + oc0) = *(uint2*)o4;
    } else {
      #pragma unroll
      for (int r = 0; r < 4; ++r){
        int oc = oc0 + r;
        float v = acc[nn][r] + bsa[r];
        v = v > 0.f ? v : 0.1f*v;
        yf[((size_t)b*CC + oc)*PP + pi] = v + resx[((size_t)b*CC + oc)*PP + pi];
      }
    }
  }
}

// ---------------------------------------------------------------------------
// k_cwm: x_cw conv via MFMA. Wave = two 16-ho M blocks, N = 64 w;
// XOR-swizzled LDS. out NCHW bf16 gated. 1D grid 2*CC*NB, b = L%NB.
// ---------------------------------------------------------------------------
__global__ __launch_bounds__(256)
void k_cwm(const bf16* __restrict__ xW, const bf16* __restrict__ wpkcw,
           const float* __restrict__ bias, const bf16* __restrict__ g,
           bf16* __restrict__ xcw, int NB){
  int L = blockIdx.x;
  int b = L % NB; int r0 = L / NB;
  int c = r0 % CC; int w0b = (r0 / CC)*64;
  int tid = threadIdx.x, lane = tid & 63, wv = tid >> 6;
  int nlo = lane & 15, quad = lane >> 4;
  __shared__ bf16 xs[66][128];
  floatx4 acc[2][4] = {};
  for (int dc = 0; dc < 3; ++dc){
    int cc = c + dc - 1;
    if (cc < 0 || cc >= CC) continue;
    __syncthreads();
    for (int idx = tid; idx < 1056; idx += 256){
      int s = idx >> 4, ch = idx & 15;
      int gw = w0b - 1 + s;
      uint4 v = make_uint4(0,0,0,0);
      if (gw >= 0 && gw < TT)
        v = *(const uint4*)(xW + (((size_t)b*CC + cc)*TT + gw)*TT + ch*8);
      *(uint4*)(&xs[s][((ch ^ (s & 7)))*8]) = v;
    }
    __syncthreads();
    #pragma unroll
    for (int dw = 0; dw < 3; ++dw){
      int t = dc*3 + dw;
      int swk = (nlo + dw) & 7;
      #pragma unroll
      for (int kk = 0; kk < 4; ++kk){
        short8 a0 = *(const short8*)(const void*)(wpkcw + (((t*4+kk)*8 + wv*2    )*64 + lane)*8);
        short8 a1 = *(const short8*)(const void*)(wpkcw + (((t*4+kk)*8 + wv*2 + 1)*64 + lane)*8);
        int pc = ((kk*4 + quad) ^ swk)*8;
        #pragma unroll
        for (int nn = 0; nn < 4; ++nn){
          short8 bf = lds8(&xs[nn*16 + nlo + dw][pc]);
          acc[0][nn] = __builtin_amdgcn_mfma_f32_16x16x32_bf16(a0, bf, acc[0][nn], 0,0,0);
          acc[1][nn] = __builtin_amdgcn_mfma_f32_16x16x32_bf16(a1, bf, acc[1][nn], 0,0,0);
        }
      }
    }
  }
  #pragma unroll
  for (int ml = 0; ml < 2; ++ml){
    int ho0 = (wv*2 + ml)*16 + quad*4;
    float4 bs = *(const float4*)(bias + ho0);
    float bsa[4] = { bs.x, bs.y, bs.z, bs.w };
    #pragma unroll
    for (int nn = 0; nn < 4; ++nn){
      int w = w0b + nn*16 + nlo;
      #pragma unroll
      for (int r = 0; r < 4; ++r){
        int ho = ho0 + r;
        float v = acc[ml][nn][r] + bsa[r];
        v = v > 0.f ? v : 0.1f*v;
        v *= b2f(g[((size_t)b*C3 + 64 + c)*PP + ho*TT + w]);
        xcw[((size_t)b*CC + c)*PP + ho*TT + w] = f2b(v);
      }
    }
  }
}

// ---------------------------------------------------------------------------
// k_hcm: x_hc conv via MFMA. Wave = two 16-wo M blocks, N = 64 c;
// XOR-swizzled LDS. out NHWC bf16 gated. 1D grid TT*NB, b = L%NB.
// ---------------------------------------------------------------------------
__global__ __launch_bounds__(256)
void k_hcm(const bf16* __restrict__ xb16, const bf16* __restrict__ wpkhc,
           const float* __restrict__ bias, const bf16* __restrict__ g,
           bf16* __restrict__ xhch, int NB){
  int L = blockIdx.x;
  int b = L % NB, h = L / NB;
  int tid = threadIdx.x, lane = tid & 63, wv = tid >> 6;
  int nlo = lane & 15, quad = lane >> 4;
  __shared__ bf16 xs[66][128];
  floatx4 acc[2][4] = {};
  for (int dh = 0; dh < 3; ++dh){
    int gh = h + dh - 1;
    __syncthreads();
    for (int idx = tid; idx < 1056; idx += 256){
      int s = idx >> 4, ch = idx & 15;
      int cc = s - 1;
      uint4 v = make_uint4(0,0,0,0);
      if (cc >= 0 && cc < CC && gh >= 0 && gh < TT)
        v = *(const uint4*)(xb16 + (((size_t)b*CC + cc)*TT + gh)*TT + ch*8);
      *(uint4*)(&xs[s][((ch ^ (s & 7)))*8]) = v;
    }
    __syncthreads();
    #pragma unroll
    for (int dc = 0; dc < 3; ++dc){
      int t = dh*3 + dc;
      int swk = (nlo + dc) & 7;
      #pragma unroll
      for (int kk = 0; kk < 4; ++kk){
        short8 a0 = *(const short8*)(const void*)(wpkhc + (((t*4+kk)*8 + wv*2    )*64 + lane)*8);
        short8 a1 = *(const short8*)(const void*)(wpkhc + (((t*4+kk)*8 + wv*2 + 1)*64 + lane)*8);
        int pc = ((kk*4 + quad) ^ swk)*8;
        #pragma unroll
        for (int nn = 0; nn < 4; ++nn){
          short8 bf = lds8(&xs[nn*16 + nlo + dc][pc]);
          acc[0][nn] = __builtin_amdgcn_mfma_f32_16x16x32_bf16(a0, bf, acc[0][nn], 0,0,0);
          acc[1][nn] = __builtin_amdgcn_mfma_f32_16x16x32_bf16(a1, bf, acc[1][nn], 0,0,0);
        }
      }
    }
  }
  #pragma unroll
  for (int ml = 0; ml < 2; ++ml){
    int wo0 = (wv*2 + ml)*16 + quad*4;
    float4 bs = *(const float4*)(bias + wo0);
    float bsa[4] = { bs.x, bs.y, bs.z, bs.w };
    #pragma unroll
    for (int nn = 0; nn < 4; ++nn){
      int c = nn*16 + nlo;
      bf16 gg[4];
      *(uint2*)gg = *(const uint2*)(g + ((size_t)b*C3 + 128 + c)*PP + h*TT + wo0);
      #pragma unroll
      for (int r = 0; r < 4; ++r){
        float v = acc[ml][nn][r] + bsa[r];
        v = v > 0.f ? v : 0.1f*v;
        xhch[((size_t)b*PP + h*TT + wo0 + r)*64 + c] = f2b(v * b2f(gg[r]));
      }
    }
  }
}

// ---------------------------------------------------------------------------
// k_downm: folded down-conv as MFMA GEMM, K=256 over (x, x_hw, x_cw, x_hc),
// plus residual x. out NHWC bf16. grid (TT, nb), block 256.
// ---------------------------------------------------------------------------
__global__ __launch_bounds__(256)
void k_downm(const bf16* __restrict__ xh, const bf16* __restrict__ xhwh,
             const bf16* __restrict__ xcwn, const bf16* __restrict__ xhch,
             const bf16* __restrict__ wpkd, const float* __restrict__ x,
             const float* __restrict__ bias, bf16* __restrict__ outh){
  int h = blockIdx.x, b = blockIdx.y;
  int tid = threadIdx.x, lane = tid & 63, wv = tid >> 6;
  int nlo = lane & 15, quad = lane >> 4;
  int p0 = h*TT;
  __shared__ bf16 xs[128][76];
  for (int idx = tid; idx < 1024; idx += 256){
    int c = idx >> 4, w8 = (idx & 15)*8;
    bf16 tmp[8];
    *(uint4*)tmp = *(const uint4*)(xcwn + ((size_t)b*CC + c)*PP + p0 + w8);
    #pragma unroll
    for (int j = 0; j < 8; ++j) xs[w8+j][c] = tmp[j];
  }
  __syncthreads();
  int n0 = wv*32;
  floatx4 acc[4][2] = {};
  #pragma unroll
  for (int kk = 0; kk < 8; ++kk){
    int s = kk >> 1;
    int ko = (kk & 1)*32 + quad*8;
    short8 bfr[2];
    #pragma unroll
    for (int nn = 0; nn < 2; ++nn){
      int p = n0 + nn*16 + nlo;
      if (s == 2){
        bfr[nn] = lds8(&xs[p][ko]);
      } else {
        const bf16* src = (s == 0) ? xh : (s == 1) ? xhwh : xhch;
        bfr[nn] = *(const short8*)(const void*)(src + ((size_t)b*PP + p0 + p)*64 + ko);
      }
    }
    #pragma unroll
    for (int mm = 0; mm < 4; ++mm){
      short8 a = *(const short8*)(const void*)(wpkd + ((kk*4+mm)*64 + lane)*8);
      acc[mm][0] = __builtin_amdgcn_mfma_f32_16x16x32_bf16(a, bfr[0], acc[mm][0], 0,0,0);
      acc[mm][1] = __builtin_amdgcn_mfma_f32_16x16x32_bf16(a, bfr[1], acc[mm][1], 0,0,0);
    }
  }
  #pragma unroll
  for (int mm = 0; mm < 4; ++mm){
    int o0 = mm*16 + quad*4;
    float4 bs = *(const float4*)(bias + o0);
    float bsa[4] = { bs.x, bs.y, bs.z, bs.w };
    #pragma unroll
    for (int nn = 0; nn < 2; ++nn){
      int p = n0 + nn*16 + nlo;
      bf16 o4[4];
      #pragma unroll
      for (int r = 0; r < 4; ++r){
        float v = acc[mm][nn][r] + bsa[r] + x[((size_t)b*CC + o0 + r)*PP + p0 + p];
        o4[r] = f2b(v);
      }
      *(uint2*)(outh + ((size_t)b*PP + p0 + p)*64 + o0) = *(uint2*)o4;
    }
  }
}

// ---------------------------------------------------------------------------
extern "C" void kernel_launch(void* const* d_in, const int* in_sizes, int n_in,
                              void* d_out, int out_size, void* d_ws, size_t ws_size,
                              hipStream_t stream) {
  const float* x      = (const float*)d_in[0];
  const float* w_hwc  = (const float*)d_in[1];
  const float* b_hwc  = (const float*)d_in[2];
  const float* w_dw   = (const float*)d_in[3];
  const float* b_dw   = (const float*)d_in[4];
  const float* w_hw   = (const float*)d_in[5];
  const float* b_hw   = (const float*)d_in[6];
  const float* w_cw   = (const float*)d_in[7];
  const float* b_cw   = (const float*)d_in[8];
  const float* w_hc   = (const float*)d_in[9];
  const float* b_hc   = (const float*)d_in[10];
  const float* w_down = (const float*)d_in[11];
  const float* b_down = (const float*)d_in[12];
  const float* w_l1   = (const float*)d_in[13];
  const float* b_l1   = (const float*)d_in[14];
  const float* w_l2   = (const float*)d_in[15];
  const float* b_l2   = (const float*)d_in[16];
  float* out = (float*)d_out;

  char* ws = (char*)d_ws;
  // ---- meta (prepacked weights) ----
  bf16*  wpkd  = (bf16*) (ws + 0);        // 32,768 B
  float* bg    = (float*)(ws + 36864);    // 6,912
  bf16*  wpkhw = (bf16*) (ws + 65536);    // 73,728
  bf16*  wpkl1 = (bf16*) (ws + 139264);   // 73,728
  bf16*  wpkl2 = (bf16*) (ws + 212992);   // 73,728
  bf16*  wpkcw = (bf16*) (ws + 294912);   // 294,912
  bf16*  wpkhc = (bf16*) (ws + 589824);   // 294,912
  bf16*  wpkgm = (bf16*) (ws + 884736);   // 294,912 -> 1,179,648

  k_wpk<<<576, 256, 0, stream>>>(w_down, w_hc, w_cw, w_hwc, w_hw, w_l1, w_l2,
                                 w_dw, b_hwc, b_dw,
                                 wpkd, wpkhw, wpkl1, wpkl2, wpkcw, wpkhc,
                                 wpkgm, bg);

  if (ws_size >= 153092096ull) {
    // ---- full-batch path (153 MB) ----
    bf16* g    = (bf16*)(ws + 2097152);     // 50,331,648 (ch 0..63 unused)
    bf16* xh   = (bf16*)(ws + 52428800);    // 16,777,216
    bf16* xW   = (bf16*)(ws + 69206016);    // 16,777,216
    bf16* xb16 = (bf16*)(ws + 85983232);    // 16,777,216
    bf16* xhwh = (bf16*)(ws + 102760448);   // 16,777,216 (NHWC)
    bf16* xcw  = (bf16*)(ws + 119537664);   // 16,777,216 (NCHW)
    bf16* xhch = (bf16*)(ws + 136314880);   // 16,777,216 (NHWC) -> 153,092,096
    bf16* outh = xW;                        // dead after k_cwm
    bf16* o1h  = xb16;                      // dead after k_hcm

    k_pack<<<dim3(TT, BB), 256, 0, stream>>>(x, xh, xb16);
    k_xw<<<dim3(CC, BB), 256, 0, stream>>>(xb16, xW);
    k_ghwm<<<2*TT*BB, 256, 0, stream>>>(xh, wpkgm, bg, b_hw, xhwh, g, BB);
    k_cwm  <<<2*CC*BB, 256, 0, stream>>>(xW, wpkcw, b_cw, g, xcw, BB);
    k_hcm  <<<TT*BB, 256, 0, stream>>>(xb16, wpkhc, b_hc, g, xhch, BB);
    k_downm<<<dim3(TT, BB), 256, 0, stream>>>(xh, xhwh, xcw, xhch, wpkd, x, b_down, outh);
    k_c3x3m<<<TT*BB, 256, 0, stream>>>(outh, wpkl1, b_l1, nullptr, o1h, nullptr, 1, BB);
    k_c3x3m<<<TT*BB, 256, 0, stream>>>(o1h, wpkl2, b_l2, x, nullptr, out, 2, BB);
  } else {
    // ---- per-batch path (~21 MB) ----
    char* P = ws + 2097152;
    bf16* g_b    = (bf16*)(P);              //  6,291,456
    bf16* xh_b   = (bf16*)(P + 6291456);    //  2,097,152
    bf16* xW_b   = (bf16*)(P + 8388608);    //  2,097,152
    bf16* xb_b   = (bf16*)(P + 10485760);   //  2,097,152
    bf16* xhwh_b = (bf16*)(P + 12582912);   //  2,097,152
    bf16* xcw_b  = (bf16*)(P + 14680064);   //  2,097,152
    bf16* xhch_b = (bf16*)(P + 16777216);   //  2,097,152 -> 18,874,368
    bf16* outh_b = xW_b;
    bf16* o1h_b  = xb_b;
    for (int b = 0; b < BB; ++b){
      const float* xb = x + (size_t)b*CC*PP;
      float* outb = out + (size_t)b*CC*PP;
      k_pack<<<dim3(TT, 1), 256, 0, stream>>>(xb, xh_b, xb_b);
      k_xw<<<dim3(CC, 1), 256, 0, stream>>>(xb_b, xW_b);
      k_ghwm<<<2*TT, 256, 0, stream>>>(xh_b, wpkgm, bg, b_hw, xhwh_b, g_b, 1);
      k_cwm  <<<2*CC, 256, 0, stream>>>(xW_b, wpkcw, b_cw, g_b, xcw_b, 1);
      k_hcm  <<<TT, 256, 0, stream>>>(xb_b, wpkhc, b_hc, g_b, xhch_b, 1);
      k_downm<<<dim3(TT, 1), 256, 0, stream>>>(xh_b, xhwh_b, xcw_b, xhch_b, wpkd, xb, b_down, outh_b);
      k_c3x3m<<<TT, 256, 0, stream>>>(outh_b, wpkl1, b_l1, nullptr, o1h_b, nullptr, 1, 1);
      k_c3x3m<<<TT, 256, 0, stream>>>(o1h_b, wpkl2, b_l2, xb, nullptr, outb, 2, 1);
    }
  }
}

// Round 12
// 284.549 us; speedup vs baseline: 1.1559x; 1.0044x over previous
//
#include <hip/hip_runtime.h>
#include <hip/hip_bf16.h>

#define BB 8
#define CC 64
#define TT 128
#define PP (TT*TT)
#define C3 192

typedef __hip_bfloat16 bf16;
typedef __attribute__((ext_vector_type(8))) short short8;
typedef __attribute__((ext_vector_type(4))) float floatx4;

__device__ __forceinline__ float b2f(bf16 v){ return __bfloat162float(v); }
__device__ __forceinline__ bf16 f2b(float v){ return __float2bfloat16(v); }
__device__ __forceinline__ short8 lds8(const bf16* p){ return *(const short8*)(const void*)p; }

// ---------------------------------------------------------------------------
// k_wpk: weight prepack into MFMA A-frag lane order.
// A[m][k] frag: m = mm*16 + (lane&15), k = kk*32 + (lane>>4)*8 + j.
// wpkd = folded down-conv weights, K=256 over (s=x,hw,cw,hc)(c).
// wpkgm = ghwm stream-major layout [wv][t2k][s][lane][8]: per (t,kk) a wave's
//         4 A-frags are 4 consecutive KB -> one base + imm offsets (VALU cut).
// bg[cls][oc] = b_dw + b1*sum_valid(w_dw) over 9 boundary classes.
// ---------------------------------------------------------------------------
__global__ void k_wpk(const float* __restrict__ w_down, const float* __restrict__ w_hc,
                      const float* __restrict__ w_cw,  const float* __restrict__ w_hwc,
                      const float* __restrict__ w_hw,  const float* __restrict__ w_l1,
                      const float* __restrict__ w_l2,  const float* __restrict__ w_dw,
                      const float* __restrict__ b_hwc, const float* __restrict__ b_dw,
                      bf16* __restrict__ wpkd,
                      bf16* __restrict__ wpkhw, bf16* __restrict__ wpkl1,
                      bf16* __restrict__ wpkl2, bf16* __restrict__ wpkcw,
                      bf16* __restrict__ wpkhc, bf16* __restrict__ wpkgm,
                      float* __restrict__ bg){
  int i = blockIdx.x*256 + threadIdx.x;
  if (i < 147456){   // cw: t=dc*3+dw ; hc: t=dh*3+dc ; M=128,K=128
    int j = i & 7, lane = (i>>3) & 63, mm = (i>>9) & 7, kk = (i>>12) & 3, t = i >> 14;
    int m = mm*16 + (lane & 15);
    int k = kk*32 + (lane>>4)*8 + j;
    wpkcw[i] = f2b(w_cw[m*1152 + k*9 + t]);
    wpkhc[i] = f2b(w_hc[m*1152 + k*9 + t]);
  }
  if (i < 147456){   // ghwm stream-major: i = ((wv*18+t2k)*4+s)*512 + lane*8 + j
    int j = i & 7, lane = (i>>3) & 63, s = (i>>9) & 3;
    int rest = i >> 11;
    int t2k = rest % 18, wv = rest / 18;
    int t = t2k >> 1, kk = t2k & 1;
    int lm = lane & 15;
    int ic = kk*32 + (lane>>4)*8 + j;
    float val;
    if (s == 0){
      val = w_hw[(wv*16 + lm)*576 + ic*9 + t];
    } else {
      int grp = (s == 1) ? wv : (s == 2) ? 4 + wv : 8 + wv;
      int oc = grp*16 + lm;
      val = w_dw[oc*9 + t] * w_hwc[oc*64 + ic];
    }
    wpkgm[i] = f2b(val);
  }
  if (i < 36864){    // hw/l1/l2: M=64,K=64, t=dh*3+dw
    int j = i & 7, lane = (i>>3) & 63, mm = (i>>9) & 3, kk = (i>>11) & 1, t = i >> 12;
    int oc = mm*16 + (lane & 15);
    int ic = kk*32 + (lane>>4)*8 + j;
    int s = oc*576 + ic*9 + t;
    wpkhw[i] = f2b(w_hw[s]);
    wpkl1[i] = f2b(w_l1[s]);
    wpkl2[i] = f2b(w_l2[s]);
  }
  if (i < 1728){     // bg[cls][oc], cls = ch*3+cw, ch/cw in {0:edge-lo,1:mid,2:edge-hi}
    int cls = i / C3, oc = i % C3;
    int ch = cls / 3, cw = cls % 3;
    float S = 0.f;
    for (int dh = (ch==0?1:0); dh <= (ch==2?1:2); ++dh)
      for (int dw = (cw==0?1:0); dw <= (cw==2?1:2); ++dw)
        S += w_dw[oc*9 + dh*3 + dw];
    bg[cls*C3 + oc] = b_dw[oc] + b_hwc[oc]*S;
  }
  if (i < 16384){    // down: M=64, K=256 (kk 0..7), k = s*64+c, w = wd[s]+wd[7-s]
    int j = i & 7, lane = (i>>3) & 63, mm = (i>>9) & 3, kk = i >> 11;  // kk 0..7
    int m = mm*16 + (lane & 15);
    int k = kk*32 + (lane>>4)*8 + j;
    int s = k >> 6, c = k & 63;
    wpkd[i] = f2b(w_down[m*512 + c*8 + s] + w_down[m*512 + c*8 + 7 - s]);
  }
}

// ---------------------------------------------------------------------------
// k_pack: x(fp32 NCHW) -> xh (NHWC bf16) + xb16 (NCHW bf16), one x read.
// ---------------------------------------------------------------------------
__global__ void k_pack(const float* __restrict__ x, bf16* __restrict__ xh,
                       bf16* __restrict__ xb16){
  int h = blockIdx.x, b = blockIdx.y;
  __shared__ float xs[64][129];
  for (int idx = threadIdx.x; idx < 2048; idx += 256){
    int c = idx >> 5, w4 = (idx & 31)*4;
    float4 v = *(const float4*)(x + ((size_t)b*CC + c)*PP + h*TT + w4);
    bf16 o4[4] = { f2b(v.x), f2b(v.y), f2b(v.z), f2b(v.w) };
    *(uint2*)(xb16 + ((size_t)b*CC + c)*PP + h*TT + w4) = *(uint2*)o4;
    xs[c][w4] = v.x; xs[c][w4+1] = v.y; xs[c][w4+2] = v.z; xs[c][w4+3] = v.w;
  }
  __syncthreads();
  for (int idx = threadIdx.x; idx < 8192; idx += 256){
    int w = idx >> 6, c = idx & 63;
    xh[(((size_t)b*TT + h)*TT + w)*64 + c] = f2b(xs[c][w]);
  }
}

// xW = [b][c][w][h] bf16 (for cw conv B-operand, h contiguous).
// Reads xb16 (bit-identical to f2b(x)) -> halves read traffic vs fp32 x.
__global__ void k_xw(const bf16* __restrict__ xb16, bf16* __restrict__ xW){
  int c = blockIdx.x, b = blockIdx.y;
  __shared__ unsigned short xs2[32][140];
  const bf16* src = xb16 + ((size_t)b*CC + c)*PP;
  unsigned short* dst = (unsigned short*)(xW + ((size_t)b*CC + c)*PP);
  for (int s = 0; s < 4; ++s){
    if (s) __syncthreads();
    for (int idx = threadIdx.x; idx < 512; idx += 256){
      int hl = idx >> 4, w8 = (idx & 15)*8;
      unsigned short tmp[8];
      *(uint4*)tmp = *(const uint4*)(src + (s*32 + hl)*TT + w8);
      #pragma unroll
      for (int j = 0; j < 8; ++j) xs2[hl][w8+j] = tmp[j];
    }
    __syncthreads();
    for (int idx = threadIdx.x; idx < 4096; idx += 256){
      int w = idx >> 5, hl = idx & 31;
      dst[w*TT + s*32 + hl] = xs2[hl][w];
    }
  }
}

// ---------------------------------------------------------------------------
// k_ghwm: fused {g-conv (folded 1x1+dw, 192 oc) + hw-conv (64 oc) + HW gating}.
// Merged form: half-row tiles, wave wv owns 4 M-frags {hw[wv], g[wv](gate,
// reg-only), g[4+wv](CW), g[8+wv](HC)} x 4 N-frags; acc[4][4].
// Weights via stream-major wpkgm: per (t,kk) one base + imm offsets 0/1/2/3KB.
// 1D grid 2*TT*NB, b = L%NB -> all blocks of batch b on one XCD.
// ---------------------------------------------------------------------------
__global__ __launch_bounds__(256)
void k_ghwm(const bf16* __restrict__ xh, const bf16* __restrict__ wpkgm,
            const float* __restrict__ bg,
            const float* __restrict__ b_hw, bf16* __restrict__ xhwh,
            bf16* __restrict__ g, int NB){
  int L = blockIdx.x;
  int b = L % NB; int r0 = L / NB;
  int h = r0 % TT; int w0b = (r0 / TT)*64;
  int tid = threadIdx.x, lane = tid & 63, wv = tid >> 6;
  int nlo = lane & 15, quad = lane >> 4;
  __shared__ bf16 xs[3][66][64];                  // 25,344 B
  for (int idx = tid; idx < 1584; idx += 256){
    int dh = idx / 528, rr = idx % 528, wi = rr >> 3, ch = rr & 7;
    int gh = h + dh - 1, gw = w0b + wi - 1;
    uint4 v = make_uint4(0,0,0,0);
    if (gh >= 0 && gh < TT && gw >= 0 && gw < TT)
      v = *(const uint4*)(xh + (((size_t)b*TT + gh)*TT + gw)*64 + ch*8);
    *(uint4*)(&xs[dh][wi][((ch ^ (wi & 7)))*8]) = v;
  }
  __syncthreads();
  const bf16* pa = wpkgm + (size_t)wv*36864 + lane*8;   // [wv][t2k][s][lane][8]
  floatx4 acc[4][4] = {};   // [ml: 0=hw, 1=gateHW, 2=gCW, 3=gHC][nn]
  #pragma unroll
  for (int t = 0; t < 9; ++t){
    int dh = t/3, dw = t%3;
    int swk = (nlo + dw) & 7;
    #pragma unroll
    for (int kk = 0; kk < 2; ++kk){
      int pc = ((kk*4 + quad) ^ swk)*8;
      short8 bfv[4];
      #pragma unroll
      for (int nn = 0; nn < 4; ++nn)
        bfv[nn] = lds8(&xs[dh][nn*16 + nlo + dw][pc]);
      const bf16* base = pa + (t*2 + kk)*2048;
      short8 a0 = *(const short8*)(const void*)(base);
      short8 a1 = *(const short8*)(const void*)(base + 512);
      short8 a2 = *(const short8*)(const void*)(base + 1024);
      short8 a3 = *(const short8*)(const void*)(base + 1536);
      #pragma unroll
      for (int nn = 0; nn < 4; ++nn){
        acc[0][nn] = __builtin_amdgcn_mfma_f32_16x16x32_bf16(a0, bfv[nn], acc[0][nn], 0,0,0);
        acc[1][nn] = __builtin_amdgcn_mfma_f32_16x16x32_bf16(a1, bfv[nn], acc[1][nn], 0,0,0);
        acc[2][nn] = __builtin_amdgcn_mfma_f32_16x16x32_bf16(a2, bfv[nn], acc[2][nn], 0,0,0);
        acc[3][nn] = __builtin_amdgcn_mfma_f32_16x16x32_bf16(a3, bfv[nn], acc[3][nn], 0,0,0);
      }
    }
  }
  int ch_cls3 = ((h == 0) ? 0 : (h == TT-1) ? 2 : 1)*3;
  int oc0 = wv*16 + quad*4;                       // local 0..63 within each group
  float4 bhw = *(const float4*)(b_hw + oc0);
  // --- xhwh = lrelu(hw + b_hw) * bf16(gateHW) ---
  #pragma unroll
  for (int nn = 0; nn < 4; ++nn){
    int w = w0b + nn*16 + nlo;
    int cw_cls = (w == 0) ? 0 : (w == TT-1) ? 2 : 1;
    const float* bgrow = bg + (ch_cls3 + cw_cls)*C3;
    float4 bg0 = *(const float4*)(bgrow + oc0);
    float bga[4] = { bg0.x, bg0.y, bg0.z, bg0.w };
    float bha[4] = { bhw.x, bhw.y, bhw.z, bhw.w };
    bf16 o4[4];
    #pragma unroll
    for (int r = 0; r < 4; ++r){
      float hv = acc[0][nn][r] + bha[r];
      hv = hv > 0.f ? hv : 0.1f*hv;
      float gv = b2f(f2b(acc[1][nn][r] + bga[r]));   // match old bf16 round-trip
      o4[r] = f2b(hv * gv);
    }
    *(uint2*)(xhwh + (((size_t)b*PP + h*TT + w))*64 + oc0) = *(uint2*)o4;
  }
  // --- gCW/gHC: acc -> LDS [2][64][72] -> dwordx4 NCHW stores ---
  __syncthreads();                                // all waves done with xs
  bf16* tb = &xs[0][0][0];                        // reuse: 2*64*72*2 = 18,432 B
  #pragma unroll
  for (int p = 0; p < 2; ++p){
    #pragma unroll
    for (int nn = 0; nn < 4; ++nn){
      int wl = nn*16 + nlo;
      int w = w0b + wl;
      int cw_cls = (w == 0) ? 0 : (w == TT-1) ? 2 : 1;
      float4 bgp = *(const float4*)(bg + (ch_cls3 + cw_cls)*C3 + 64 + p*64 + oc0);
      float bga[4] = { bgp.x, bgp.y, bgp.z, bgp.w };
      #pragma unroll
      for (int r = 0; r < 4; ++r)
        tb[(p*64 + oc0 + r)*72 + wl] = f2b(acc[2+p][nn][r] + bga[r]);
    }
  }
  __syncthreads();
  #pragma unroll
  for (int i = 0; i < 4; ++i){
    int idx = i*256 + tid;                        // 0..1023 = 128 rows x 8 chunks
    int row = idx >> 3, wc = (idx & 7)*8;
    uint4 v = *(const uint4*)(tb + row*72 + wc);
    *(uint4*)(g + ((size_t)b*C3 + 64 + row)*PP + h*TT + w0b + wc) = v;
  }
}

// ---------------------------------------------------------------------------
// k_c3x3m: MFMA 64->64 3x3 conv over NHWC bf16 input. Wave = one 16-oc M
// block, N = 128; XOR-swizzled LDS. 1D grid TT*NB, b = L%NB (XCD locality).
// mode 1: yb NHWC = lrelu; 2: yf NCHW fp32 = lrelu+res
// ---------------------------------------------------------------------------
__global__ __launch_bounds__(256)
void k_c3x3m(const bf16* __restrict__ in, const bf16* __restrict__ wpk,
             const float* __restrict__ bias,
             const float* __restrict__ resx, bf16* __restrict__ yb,
             float* __restrict__ yf, int mode, int NB){
  int L = blockIdx.x;
  int b = L % NB, h = L / NB;
  int tid = threadIdx.x, lane = tid & 63, wv = tid >> 6;
  int nlo = lane & 15, quad = lane >> 4;
  __shared__ bf16 xs[3][130][64];
  for (int idx = tid; idx < 3120; idx += 256){
    int dh = idx / 1040, r = idx % 1040, wi = r >> 3, ch = r & 7;
    int gh = h + dh - 1, gw = wi - 1;
    uint4 v = make_uint4(0,0,0,0);
    if (gh >= 0 && gh < TT && gw >= 0 && gw < TT)
      v = *(const uint4*)(in + (((size_t)b*TT + gh)*TT + gw)*64 + ch*8);
    *(uint4*)(&xs[dh][wi][((ch ^ (wi & 7)))*8]) = v;
  }
  __syncthreads();
  floatx4 acc[8] = {};
  #pragma unroll
  for (int t = 0; t < 9; ++t){
    int dh = t/3, dw = t%3;
    int swk = (nlo + dw) & 7;
    #pragma unroll
    for (int kk = 0; kk < 2; ++kk){
      short8 a = *(const short8*)(const void*)(wpk + (((t*2+kk)*4+wv)*64 + lane)*8);
      int pc = ((kk*4 + quad) ^ swk)*8;
      #pragma unroll
      for (int nn = 0; nn < 8; ++nn){
        short8 bf = lds8(&xs[dh][nn*16 + nlo + dw][pc]);
        acc[nn] = __builtin_amdgcn_mfma_f32_16x16x32_bf16(a, bf, acc[nn], 0,0,0);
      }
    }
  }
  int oc0 = wv*16 + quad*4;
  float4 bs = *(const float4*)(bias + oc0);
  float bsa[4] = { bs.x, bs.y, bs.z, bs.w };
  #pragma unroll
  for (int nn = 0; nn < 8; ++nn){
    int w = nn*16 + nlo;
    int pi = h*TT + w;
    if (mode == 1){
      bf16 o4[4];
      #pragma unroll
      for (int r = 0; r < 4; ++r){
        float v = acc[nn][r] + bsa[r];
        o4[r] = f2b(v > 0.f ? v : 0.1f*v);
      }
      *(uint2*)(yb + ((size_t)b*PP + pi)*64 + oc0) = *(uint2*)o4;
    } else {
      #pragma unroll
      for (int r = 0; r < 4; ++r){
        int oc = oc0 + r;
        float v = acc[nn][r] + bsa[r];
        v = v > 0.f ? v : 0.1f*v;
        yf[((size_t)b*CC + oc)*PP + pi] = v + resx[((size_t)b*CC + oc)*PP + pi];
      }
    }
  }
}

// ---------------------------------------------------------------------------
// k_cwm: x_cw conv via MFMA. Wave = two 16-ho M blocks, N = 64 w;
// XOR-swizzled LDS. out NCHW bf16 gated. 1D grid 2*CC*NB, b = L%NB.
// ---------------------------------------------------------------------------
__global__ __launch_bounds__(256)
void k_cwm(const bf16* __restrict__ xW, const bf16* __restrict__ wpkcw,
           const float* __restrict__ bias, const bf16* __restrict__ g,
           bf16* __restrict__ xcw, int NB){
  int L = blockIdx.x;
  int b = L % NB; int r0 = L / NB;
  int c = r0 % CC; int w0b = (r0 / CC)*64;
  int tid = threadIdx.x, lane = tid & 63, wv = tid >> 6;
  int nlo = lane & 15, quad = lane >> 4;
  __shared__ bf16 xs[66][128];
  floatx4 acc[2][4] = {};
  for (int dc = 0; dc < 3; ++dc){
    int cc = c + dc - 1;
    if (cc < 0 || cc >= CC) continue;
    __syncthreads();
    for (int idx = tid; idx < 1056; idx += 256){
      int s = idx >> 4, ch = idx & 15;
      int gw = w0b - 1 + s;
      uint4 v = make_uint4(0,0,0,0);
      if (gw >= 0 && gw < TT)
        v = *(const uint4*)(xW + (((size_t)b*CC + cc)*TT + gw)*TT + ch*8);
      *(uint4*)(&xs[s][((ch ^ (s & 7)))*8]) = v;
    }
    __syncthreads();
    #pragma unroll
    for (int dw = 0; dw < 3; ++dw){
      int t = dc*3 + dw;
      int swk = (nlo + dw) & 7;
      #pragma unroll
      for (int kk = 0; kk < 4; ++kk){
        short8 a0 = *(const short8*)(const void*)(wpkcw + (((t*4+kk)*8 + wv*2    )*64 + lane)*8);
        short8 a1 = *(const short8*)(const void*)(wpkcw + (((t*4+kk)*8 + wv*2 + 1)*64 + lane)*8);
        int pc = ((kk*4 + quad) ^ swk)*8;
        #pragma unroll
        for (int nn = 0; nn < 4; ++nn){
          short8 bf = lds8(&xs[nn*16 + nlo + dw][pc]);
          acc[0][nn] = __builtin_amdgcn_mfma_f32_16x16x32_bf16(a0, bf, acc[0][nn], 0,0,0);
          acc[1][nn] = __builtin_amdgcn_mfma_f32_16x16x32_bf16(a1, bf, acc[1][nn], 0,0,0);
        }
      }
    }
  }
  #pragma unroll
  for (int ml = 0; ml < 2; ++ml){
    int ho0 = (wv*2 + ml)*16 + quad*4;
    float4 bs = *(const float4*)(bias + ho0);
    float bsa[4] = { bs.x, bs.y, bs.z, bs.w };
    #pragma unroll
    for (int nn = 0; nn < 4; ++nn){
      int w = w0b + nn*16 + nlo;
      #pragma unroll
      for (int r = 0; r < 4; ++r){
        int ho = ho0 + r;
        float v = acc[ml][nn][r] + bsa[r];
        v = v > 0.f ? v : 0.1f*v;
        v *= b2f(g[((size_t)b*C3 + 64 + c)*PP + ho*TT + w]);
        xcw[((size_t)b*CC + c)*PP + ho*TT + w] = f2b(v);
      }
    }
  }
}

// ---------------------------------------------------------------------------
// k_hcdm: FUSED {x_hc conv + gate} + {folded down-conv GEMM + residual}.
// Per (h,b) block: hcm phase (stage xb16 halo in bufC-as-[66][128], MFMA,
// gate) -> gated xhch written to LDS tb[128][72] (pixel-major = downm B-frag
// layout; never touches HBM) -> stage xcw transpose in bufC[128][76] ->
// downm K=256 GEMM (s0 xh, s1 xhwh global; s2 bufC, s3 tb LDS) + x residual
// -> outh NHWC bf16. Removes the 16.7MB xhch tensor (33.5MB HBM round trip)
// and one dispatch. LDS 37.9KB. 1D grid TT*NB, b = L%NB (XCD locality).
// ---------------------------------------------------------------------------
__global__ __launch_bounds__(256)
void k_hcdm(const bf16* __restrict__ xb16, const bf16* __restrict__ wpkhc,
            const float* __restrict__ b_hc, const bf16* __restrict__ g,
            const bf16* __restrict__ xh, const bf16* __restrict__ xhwh,
            const bf16* __restrict__ xcwn, const bf16* __restrict__ wpkd,
            const float* __restrict__ x, const float* __restrict__ b_down,
            bf16* __restrict__ outh, int NB){
  int L = blockIdx.x;
  int b = L % NB, h = L / NB;
  int tid = threadIdx.x, lane = tid & 63, wv = tid >> 6;
  int nlo = lane & 15, quad = lane >> 4;
  __shared__ bf16 shm[9728 + 9216];     // bufC [128][76] (19456B) + tb [128][72] (18432B)
  bf16* bufC = shm;
  bf16* tb   = shm + 9728;
  // ================= hcm phase (staging buffer aliases bufC) =================
  bf16 (*xs)[128] = (bf16(*)[128])bufC;           // [66][128] = 16,896B <= bufC
  floatx4 acc[2][4] = {};
  for (int dh = 0; dh < 3; ++dh){
    int gh = h + dh - 1;
    __syncthreads();
    for (int idx = tid; idx < 1056; idx += 256){
      int s = idx >> 4, ch = idx & 15;
      int cc = s - 1;
      uint4 v = make_uint4(0,0,0,0);
      if (cc >= 0 && cc < CC && gh >= 0 && gh < TT)
        v = *(const uint4*)(xb16 + (((size_t)b*CC + cc)*TT + gh)*TT + ch*8);
      *(uint4*)(&xs[s][((ch ^ (s & 7)))*8]) = v;
    }
    __syncthreads();
    #pragma unroll
    for (int dc = 0; dc < 3; ++dc){
      int t = dh*3 + dc;
      int swk = (nlo + dc) & 7;
      #pragma unroll
      for (int kk = 0; kk < 4; ++kk){
        short8 a0 = *(const short8*)(const void*)(wpkhc + (((t*4+kk)*8 + wv*2    )*64 + lane)*8);
        short8 a1 = *(const short8*)(const void*)(wpkhc + (((t*4+kk)*8 + wv*2 + 1)*64 + lane)*8);
        int pc = ((kk*4 + quad) ^ swk)*8;
        #pragma unroll
        for (int nn = 0; nn < 4; ++nn){
          short8 bf = lds8(&xs[nn*16 + nlo + dc][pc]);
          acc[0][nn] = __builtin_amdgcn_mfma_f32_16x16x32_bf16(a0, bf, acc[0][nn], 0,0,0);
          acc[1][nn] = __builtin_amdgcn_mfma_f32_16x16x32_bf16(a1, bf, acc[1][nn], 0,0,0);
        }
      }
    }
  }
  // gate + write gated xhch into tb[pixel][ch] (downm B-frag layout)
  #pragma unroll
  for (int ml = 0; ml < 2; ++ml){
    int wo0 = (wv*2 + ml)*16 + quad*4;
    float4 bs = *(const float4*)(b_hc + wo0);
    float bsa[4] = { bs.x, bs.y, bs.z, bs.w };
    #pragma unroll
    for (int nn = 0; nn < 4; ++nn){
      int c = nn*16 + nlo;
      bf16 gg[4];
      *(uint2*)gg = *(const uint2*)(g + ((size_t)b*C3 + 128 + c)*PP + h*TT + wo0);
      #pragma unroll
      for (int r = 0; r < 4; ++r){
        float v = acc[ml][nn][r] + bsa[r];
        v = v > 0.f ? v : 0.1f*v;
        tb[(wo0 + r)*72 + c] = f2b(v * b2f(gg[r]));
      }
    }
  }
  __syncthreads();   // tb complete; all MFMA reads of bufC(xs) retired
  // ================= downm phase =================
  int p0 = h*TT;
  for (int idx = tid; idx < 1024; idx += 256){
    int c = idx >> 4, w8 = (idx & 15)*8;
    bf16 tmp[8];
    *(uint4*)tmp = *(const uint4*)(xcwn + ((size_t)b*CC + c)*PP + p0 + w8);
    #pragma unroll
    for (int j = 0; j < 8; ++j) bufC[(w8+j)*76 + c] = tmp[j];
  }
  __syncthreads();
  int n0 = wv*32;
  floatx4 acc2[4][2] = {};
  #pragma unroll
  for (int kk = 0; kk < 8; ++kk){
    int s = kk >> 1;
    int ko = (kk & 1)*32 + quad*8;
    short8 bfr[2];
    #pragma unroll
    for (int nn = 0; nn < 2; ++nn){
      int p = n0 + nn*16 + nlo;
      if (s == 2){
        bfr[nn] = lds8(&bufC[p*76 + ko]);
      } else if (s == 3){
        bfr[nn] = lds8(&tb[p*72 + ko]);
      } else {
        const bf16* src = (s == 0) ? xh : xhwh;
        bfr[nn] = *(const short8*)(const void*)(src + ((size_t)b*PP + p0 + p)*64 + ko);
      }
    }
    #pragma unroll
    for (int mm = 0; mm < 4; ++mm){
      short8 a = *(const short8*)(const void*)(wpkd + ((kk*4+mm)*64 + lane)*8);
      acc2[mm][0] = __builtin_amdgcn_mfma_f32_16x16x32_bf16(a, bfr[0], acc2[mm][0], 0,0,0);
      acc2[mm][1] = __builtin_amdgcn_mfma_f32_16x16x32_bf16(a, bfr[1], acc2[mm][1], 0,0,0);
    }
  }
  #pragma unroll
  for (int mm = 0; mm < 4; ++mm){
    int o0 = mm*16 + quad*4;
    float4 bs = *(const float4*)(b_down + o0);
    float bsa[4] = { bs.x, bs.y, bs.z, bs.w };
    #pragma unroll
    for (int nn = 0; nn < 2; ++nn){
      int p = n0 + nn*16 + nlo;
      bf16 o4[4];
      #pragma unroll
      for (int r = 0; r < 4; ++r){
        float v = acc2[mm][nn][r] + bsa[r] + x[((size_t)b*CC + o0 + r)*PP + p0 + p];
        o4[r] = f2b(v);
      }
      *(uint2*)(outh + ((size_t)b*PP + p0 + p)*64 + o0) = *(uint2*)o4;
    }
  }
}

// ---------------------------------------------------------------------------
extern "C" void kernel_launch(void* const* d_in, const int* in_sizes, int n_in,
                              void* d_out, int out_size, void* d_ws, size_t ws_size,
                              hipStream_t stream) {
  const float* x      = (const float*)d_in[0];
  const float* w_hwc  = (const float*)d_in[1];
  const float* b_hwc  = (const float*)d_in[2];
  const float* w_dw   = (const float*)d_in[3];
  const float* b_dw   = (const float*)d_in[4];
  const float* w_hw   = (const float*)d_in[5];
  const float* b_hw   = (const float*)d_in[6];
  const float* w_cw   = (const float*)d_in[7];
  const float* b_cw   = (const float*)d_in[8];
  const float* w_hc   = (const float*)d_in[9];
  const float* b_hc   = (const float*)d_in[10];
  const float* w_down = (const float*)d_in[11];
  const float* b_down = (const float*)d_in[12];
  const float* w_l1   = (const float*)d_in[13];
  const float* b_l1   = (const float*)d_in[14];
  const float* w_l2   = (const float*)d_in[15];
  const float* b_l2   = (const float*)d_in[16];
  float* out = (float*)d_out;

  char* ws = (char*)d_ws;
  // ---- meta (prepacked weights) ----
  bf16*  wpkd  = (bf16*) (ws + 0);        // 32,768 B
  float* bg    = (float*)(ws + 36864);    // 6,912
  bf16*  wpkhw = (bf16*) (ws + 65536);    // 73,728
  bf16*  wpkl1 = (bf16*) (ws + 139264);   // 73,728
  bf16*  wpkl2 = (bf16*) (ws + 212992);   // 73,728
  bf16*  wpkcw = (bf16*) (ws + 294912);   // 294,912
  bf16*  wpkhc = (bf16*) (ws + 589824);   // 294,912
  bf16*  wpkgm = (bf16*) (ws + 884736);   // 294,912 -> 1,179,648

  k_wpk<<<576, 256, 0, stream>>>(w_down, w_hc, w_cw, w_hwc, w_hw, w_l1, w_l2,
                                 w_dw, b_hwc, b_dw,
                                 wpkd, wpkhw, wpkl1, wpkl2, wpkcw, wpkhc,
                                 wpkgm, bg);

  if (ws_size >= 153092096ull) {
    // ---- full-batch path ----
    bf16* g    = (bf16*)(ws + 2097152);     // 50,331,648 (ch 0..63 unused)
    bf16* xh   = (bf16*)(ws + 52428800);    // 16,777,216
    bf16* xW   = (bf16*)(ws + 69206016);    // 16,777,216
    bf16* xb16 = (bf16*)(ws + 85983232);    // 16,777,216
    bf16* xhwh = (bf16*)(ws + 102760448);   // 16,777,216 (NHWC)
    bf16* xcw  = (bf16*)(ws + 119537664);   // 16,777,216 (NCHW)
    bf16* outh = xW;                        // dead after k_cwm
    bf16* o1h  = xb16;                      // dead after k_hcdm

    k_pack<<<dim3(TT, BB), 256, 0, stream>>>(x, xh, xb16);
    k_xw<<<dim3(CC, BB), 256, 0, stream>>>(xb16, xW);
    k_ghwm<<<2*TT*BB, 256, 0, stream>>>(xh, wpkgm, bg, b_hw, xhwh, g, BB);
    k_cwm  <<<2*CC*BB, 256, 0, stream>>>(xW, wpkcw, b_cw, g, xcw, BB);
    k_hcdm<<<TT*BB, 256, 0, stream>>>(xb16, wpkhc, b_hc, g, xh, xhwh, xcw,
                                      wpkd, x, b_down, outh, BB);
    k_c3x3m<<<TT*BB, 256, 0, stream>>>(outh, wpkl1, b_l1, nullptr, o1h, nullptr, 1, BB);
    k_c3x3m<<<TT*BB, 256, 0, stream>>>(o1h, wpkl2, b_l2, x, nullptr, out, 2, BB);
  } else {
    // ---- per-batch path ----
    char* P = ws + 2097152;
    bf16* g_b    = (bf16*)(P);              //  6,291,456
    bf16* xh_b   = (bf16*)(P + 6291456);    //  2,097,152
    bf16* xW_b   = (bf16*)(P + 8388608);    //  2,097,152
    bf16* xb_b   = (bf16*)(P + 10485760);   //  2,097,152
    bf16* xhwh_b = (bf16*)(P + 12582912);   //  2,097,152
    bf16* xcw_b  = (bf16*)(P + 14680064);   //  2,097,152 -> 16,777,216
    bf16* outh_b = xW_b;
    bf16* o1h_b  = xb_b;
    for (int b = 0; b < BB; ++b){
      const float* xb = x + (size_t)b*CC*PP;
      float* outb = out + (size_t)b*CC*PP;
      k_pack<<<dim3(TT, 1), 256, 0, stream>>>(xb, xh_b, xb_b);
      k_xw<<<dim3(CC, 1), 256, 0, stream>>>(xb_b, xW_b);
      k_ghwm<<<2*TT, 256, 0, stream>>>(xh_b, wpkgm, bg, b_hw, xhwh_b, g_b, 1);
      k_cwm  <<<2*CC, 256, 0, stream>>>(xW_b, wpkcw, b_cw, g_b, xcw_b, 1);
      k_hcdm<<<TT, 256, 0, stream>>>(xb_b, wpkhc, b_hc, g_b, xh_b, xhwh_b, xcw_b,
                                     wpkd, xb, b_down, outh_b, 1);
      k_c3x3m<<<TT, 256, 0, stream>>>(outh_b, wpkl1, b_l1, nullptr, o1h_b, nullptr, 1, 1);
      k_c3x3m<<<TT, 256, 0, stream>>>(o1h_b, wpkl2, b_l2, xb, nullptr, outb, 2, 1);
    }
  }
}